// Round 1
// baseline (6667.146 us; speedup 1.0000x reference)
//
#include <hip/hip_runtime.h>

// Problem constants (match reference file)
#define N_NODES  100000
#define N_EDGESC 1600000
#define EMB      128
#define N_GRAPHS 128
#define G_FEAT   32

// Order-preserving float -> uint key for atomicMax-based float max.
__device__ __forceinline__ unsigned fkey(float f) {
  unsigned u = __float_as_uint(f);
  return (u & 0x80000000u) ? ~u : (u | 0x80000000u);
}
__device__ __forceinline__ float fkey_inv(unsigned k) {
  return (k & 0x80000000u) ? __uint_as_float(k & 0x7FFFFFFFu)
                           : __uint_as_float(~k);
}

// One thread per (edge, 4-dim group): gather feat[src], atomicAdd into agg[tgt].
// dim-group 0 also bumps the per-target edge count (only on layer 0).
__global__ void scatter_kernel(const float* __restrict__ feat,
                               const int* __restrict__ srci,
                               const int* __restrict__ tgti,
                               float* __restrict__ agg,
                               float* __restrict__ cnt,
                               int do_cnt) {
  long long gid = (long long)blockIdx.x * blockDim.x + threadIdx.x;
  int e = (int)(gid >> 5);
  if (e >= N_EDGESC) return;
  int dg = ((int)gid & 31) * 4;
  int s = srci[e];
  int t = tgti[e];
  float4 v = *reinterpret_cast<const float4*>(feat + (long long)s * EMB + dg);
  float* a = agg + (long long)t * EMB + dg;
  atomicAdd(a + 0, v.x);
  atomicAdd(a + 1, v.y);
  atomicAdd(a + 2, v.z);
  atomicAdd(a + 3, v.w);
  if (do_cnt && ((gid & 31) == 0)) atomicAdd(cnt + t, 1.0f);
}

// out = [relu]( (agg/cnt) @ Wl + bl + x @ Wr ), 32 nodes per 256-thread block.
// POOL: instead of writing h, atomically accumulate graph mean-sum / max.
template <bool RELU, bool POOL>
__global__ __launch_bounds__(256) void node_kernel(
    const float* __restrict__ agg, const float* __restrict__ cnt,
    const float* __restrict__ x, const float* __restrict__ Wl,
    const float* __restrict__ bl, const float* __restrict__ Wr,
    const int* __restrict__ batch, float* __restrict__ hout,
    float* __restrict__ gsum, unsigned* __restrict__ gmax) {
  __shared__ float sA[32][EMB];
  __shared__ float sX[32][EMB];
  __shared__ float sInv[32];
  int t = threadIdx.x;
  int base = blockIdx.x * 32;  // N_NODES % 32 == 0 (100000 = 3125*32)
  if (t < 32) sInv[t] = 1.0f / fmaxf(cnt[base + t], 1.0f);
  __syncthreads();
  // Stage agg (pre-scaled by 1/cnt) and x tiles: 32 rows x 128 f32 each.
  for (int i = t; i < 32 * EMB / 4; i += 256) {
    int n = i >> 5;          // row 0..31
    int c = (i & 31) * 4;    // col group
    float4 av = *reinterpret_cast<const float4*>(agg + (long long)(base + n) * EMB + c);
    float inv = sInv[n];
    av.x *= inv; av.y *= inv; av.z *= inv; av.w *= inv;
    *reinterpret_cast<float4*>(&sA[n][c]) = av;
    *reinterpret_cast<float4*>(&sX[n][c]) =
        *reinterpret_cast<const float4*>(x + (long long)(base + n) * EMB + c);
  }
  __syncthreads();

  int tx = t & 31, ty = t >> 5;  // tx -> 4 output dims, ty -> 4 nodes
  int d0 = tx * 4;
  float acc[4][4];
#pragma unroll
  for (int a = 0; a < 4; a++)
#pragma unroll
    for (int b = 0; b < 4; b++) acc[a][b] = 0.0f;

  for (int k = 0; k < EMB; k++) {
    float4 wl = *reinterpret_cast<const float4*>(Wl + k * EMB + d0);
    float4 wr = *reinterpret_cast<const float4*>(Wr + k * EMB + d0);
#pragma unroll
    for (int nn = 0; nn < 4; nn++) {
      float av = sA[ty * 4 + nn][k];
      float xv = sX[ty * 4 + nn][k];
      acc[nn][0] += av * wl.x + xv * wr.x;
      acc[nn][1] += av * wl.y + xv * wr.y;
      acc[nn][2] += av * wl.z + xv * wr.z;
      acc[nn][3] += av * wl.w + xv * wr.w;
    }
  }

  float4 bias = *reinterpret_cast<const float4*>(bl + d0);
#pragma unroll
  for (int nn = 0; nn < 4; nn++) {
    int node = base + ty * 4 + nn;
    float v0 = acc[nn][0] + bias.x;
    float v1 = acc[nn][1] + bias.y;
    float v2 = acc[nn][2] + bias.z;
    float v3 = acc[nn][3] + bias.w;
    if (RELU) {
      v0 = fmaxf(v0, 0.0f); v1 = fmaxf(v1, 0.0f);
      v2 = fmaxf(v2, 0.0f); v3 = fmaxf(v3, 0.0f);
    }
    if (POOL) {
      int b = batch[node];
      float* gs = gsum + b * EMB + d0;
      atomicAdd(gs + 0, v0); atomicAdd(gs + 1, v1);
      atomicAdd(gs + 2, v2); atomicAdd(gs + 3, v3);
      unsigned* gm = gmax + b * EMB + d0;
      atomicMax(gm + 0, fkey(v0)); atomicMax(gm + 1, fkey(v1));
      atomicMax(gm + 2, fkey(v2)); atomicMax(gm + 3, fkey(v3));
    } else {
      float4 o = make_float4(v0, v1, v2, v3);
      *reinterpret_cast<float4*>(hout + (long long)node * EMB + d0) = o;
    }
  }
}

__global__ void gcnt_kernel(const int* __restrict__ batch,
                            float* __restrict__ gcnt) {
  int i = blockIdx.x * blockDim.x + threadIdx.x;
  if (i < N_NODES) atomicAdd(gcnt + batch[i], 1.0f);
}

// One block per graph, 128 threads = one per embedding dim.
__global__ __launch_bounds__(128) void readout_kernel(
    const float* __restrict__ gsum, const unsigned* __restrict__ gmax,
    const float* __restrict__ gcnt, const float* __restrict__ gfeat,
    const float* __restrict__ Wg, const float* __restrict__ bg,
    const float* __restrict__ Wo, const float* __restrict__ bo,
    float* __restrict__ out) {
  int g = blockIdx.x, d = threadIdx.x;
  float mean = gsum[g * EMB + d] / fmaxf(gcnt[g], 1.0f);
  float mx = fkey_inv(gmax[g * EMB + d]);
  float gfe = bg[d];
#pragma unroll
  for (int k = 0; k < G_FEAT; k++) gfe += gfeat[g * G_FEAT + k] * Wg[k * EMB + d];
  float l0 = mean * Wo[d * 2 + 0] + mx * Wo[(EMB + d) * 2 + 0] +
             gfe * Wo[(2 * EMB + d) * 2 + 0];
  float l1 = mean * Wo[d * 2 + 1] + mx * Wo[(EMB + d) * 2 + 1] +
             gfe * Wo[(2 * EMB + d) * 2 + 1];
  __shared__ float s0[128], s1[128];
  s0[d] = l0; s1[d] = l1;
  __syncthreads();
  for (int off = 64; off > 0; off >>= 1) {
    if (d < off) { s0[d] += s0[d + off]; s1[d] += s1[d + off]; }
    __syncthreads();
  }
  if (d == 0) {
    float a = s0[0] + bo[0];
    float b = s1[0] + bo[1];
    float m = fmaxf(a, b);
    float lse = m + logf(expf(a - m) + expf(b - m));
    out[g * 2 + 0] = a - lse;
    out[g * 2 + 1] = b - lse;
  }
}

extern "C" void kernel_launch(void* const* d_in, const int* in_sizes, int n_in,
                              void* d_out, int out_size, void* d_ws,
                              size_t ws_size, hipStream_t stream) {
  const float* x     = (const float*)d_in[0];
  const int*   edges = (const int*)d_in[1];
  const int*   batch = (const int*)d_in[2];
  const float* gfeat = (const float*)d_in[3];
  const float* W_l0  = (const float*)d_in[4];
  const float* b_l0  = (const float*)d_in[5];
  const float* W_r0  = (const float*)d_in[6];
  const float* W_l1  = (const float*)d_in[7];
  const float* b_l1  = (const float*)d_in[8];
  const float* W_r1  = (const float*)d_in[9];
  const float* W_g   = (const float*)d_in[10];
  const float* b_g   = (const float*)d_in[11];
  const float* W_o   = (const float*)d_in[12];
  const float* b_o   = (const float*)d_in[13];
  const int* srci = edges;
  const int* tgti = edges + N_EDGESC;

  // Workspace layout: [agg | cnt | gsum | gmax | gcnt | h]
  char* ws = (char*)d_ws;
  float*    agg  = (float*)ws;                           // N*128
  float*    cnt  = agg + (size_t)N_NODES * EMB;          // N
  float*    gsum = cnt + N_NODES;                        // 128*128
  unsigned* gmax = (unsigned*)(gsum + N_GRAPHS * EMB);   // 128*128
  float*    gcnt = (float*)(gmax + N_GRAPHS * EMB);      // 128
  float*    h    = gcnt + N_GRAPHS;                      // N*128

  // Zero everything up through gcnt (agg, cnt, gsum, gmax-keys, gcnt).
  size_t zbytes = (size_t)((char*)(gcnt + N_GRAPHS) - ws);
  hipMemsetAsync(d_ws, 0, zbytes, stream);

  dim3 b256(256);
  int sgrid = (N_EDGESC * 32) / 256;  // 200000 blocks, exact

  // Layer 0
  scatter_kernel<<<sgrid, b256, 0, stream>>>(x, srci, tgti, agg, cnt, 1);
  node_kernel<true, false><<<N_NODES / 32, b256, 0, stream>>>(
      agg, cnt, x, W_l0, b_l0, W_r0, nullptr, h, nullptr, nullptr);

  // Layer 1 (reuse agg; cnt unchanged — same edge targets)
  hipMemsetAsync(agg, 0, (size_t)N_NODES * EMB * sizeof(float), stream);
  scatter_kernel<<<sgrid, b256, 0, stream>>>(h, srci, tgti, agg, cnt, 0);
  gcnt_kernel<<<(N_NODES + 255) / 256, b256, 0, stream>>>(batch, gcnt);
  node_kernel<false, true><<<N_NODES / 32, b256, 0, stream>>>(
      agg, cnt, h, W_l1, b_l1, W_r1, batch, nullptr, gsum, gmax);

  // Readout
  readout_kernel<<<N_GRAPHS, 128, 0, stream>>>(gsum, gmax, gcnt, gfeat, W_g,
                                               b_g, W_o, b_o, (float*)d_out);
}

// Round 3
// 1786.631 us; speedup vs baseline: 3.7317x; 3.7317x over previous
//
#include <hip/hip_runtime.h>

// Problem constants (match reference file)
#define N_NODES  100000
#define N_EDGESC 1600000
#define EMB      128
#define N_GRAPHS 128
#define G_FEAT   32
#define SCAN_CHUNK 1024
#define SCAN_NBLK  ((N_NODES + SCAN_CHUNK - 1) / SCAN_CHUNK)  // 98

// Order-preserving float -> uint key for atomicMax-based float max.
__device__ __forceinline__ unsigned fkey(float f) {
  unsigned u = __float_as_uint(f);
  return (u & 0x80000000u) ? ~u : (u | 0x80000000u);
}
__device__ __forceinline__ float fkey_inv(unsigned k) {
  return (k & 0x80000000u) ? __uint_as_float(k & 0x7FFFFFFFu)
                           : __uint_as_float(~k);
}

// ---------------- CSR build ----------------

__global__ void hist_kernel(const int* __restrict__ tgti, int* __restrict__ deg) {
  int e = blockIdx.x * blockDim.x + threadIdx.x;
  if (e < N_EDGESC) atomicAdd(&deg[tgti[e]], 1);
}

// Per-block exclusive scan of 1024-elem chunks (4 elems/thread, 256 threads).
__global__ __launch_bounds__(256) void scan1_kernel(const int* __restrict__ deg,
                                                    int* __restrict__ partial,
                                                    int* __restrict__ blocksum) {
  __shared__ int sh[256];
  int t = threadIdx.x;
  int idx0 = blockIdx.x * SCAN_CHUNK + t * 4;
  int v[4], s = 0;
#pragma unroll
  for (int i = 0; i < 4; i++) {
    int idx = idx0 + i;
    v[i] = (idx < N_NODES) ? deg[idx] : 0;
    s += v[i];
  }
  sh[t] = s;
  __syncthreads();
  for (int off = 1; off < 256; off <<= 1) {
    int val = (t >= off) ? sh[t - off] : 0;
    __syncthreads();
    if (t >= off) sh[t] += val;
    __syncthreads();
  }
  int run = sh[t] - s;  // exclusive prefix of this thread's 4-group
#pragma unroll
  for (int i = 0; i < 4; i++) {
    int idx = idx0 + i;
    if (idx < N_NODES) partial[idx] = run;
    run += v[i];
  }
  if (t == 255) blocksum[blockIdx.x] = sh[255];
}

// Exclusive scan of the 98 block sums (single block, 128 threads).
__global__ __launch_bounds__(128) void scan2_kernel(int* __restrict__ blocksum) {
  __shared__ int sh[128];
  int t = threadIdx.x;
  int v = (t < SCAN_NBLK) ? blocksum[t] : 0;
  sh[t] = v;
  __syncthreads();
  for (int off = 1; off < 128; off <<= 1) {
    int val = (t >= off) ? sh[t - off] : 0;
    __syncthreads();
    if (t >= off) sh[t] += val;
    __syncthreads();
  }
  if (t < SCAN_NBLK) blocksum[t] = sh[t] - v;  // exclusive
}

__global__ void scan3_kernel(const int* __restrict__ partial,
                             const int* __restrict__ blocksum,
                             int* __restrict__ rowstart) {
  int i = blockIdx.x * blockDim.x + threadIdx.x;
  if (i < N_NODES) rowstart[i] = partial[i] + blocksum[i / SCAN_CHUNK];
  if (i == 0) rowstart[N_NODES] = N_EDGESC;
}

__global__ void fill_kernel(const int* __restrict__ srci,
                            const int* __restrict__ tgti,
                            const int* __restrict__ rowstart,
                            int* __restrict__ cursor, int* __restrict__ ebuf) {
  int e = blockIdx.x * blockDim.x + threadIdx.x;
  if (e >= N_EDGESC) return;
  int t = tgti[e];
  int pos = atomicAdd(&cursor[t], 1);
  ebuf[rowstart[t] + pos] = srci[e];
}

// ---------------- mean aggregation (gather-side, no atomics) ----------------
// One wave per node; lane l owns dims 2l..2l+1. agg pre-scaled by 1/deg.
__global__ __launch_bounds__(256) void agg_kernel(const float* __restrict__ feat,
                                                  const int* __restrict__ ebuf,
                                                  const int* __restrict__ rowstart,
                                                  float* __restrict__ agg) {
  int node = (blockIdx.x * 256 + threadIdx.x) >> 6;  // global wave id
  if (node >= N_NODES) return;
  int lane = threadIdx.x & 63;
  int beg = rowstart[node], end = rowstart[node + 1];
  int d = lane * 2;
  float ax = 0.0f, ay = 0.0f;
  for (int j = beg; j < end; j++) {
    int s = ebuf[j];  // wave-uniform -> broadcast
    float2 v = *reinterpret_cast<const float2*>(feat + (long long)s * EMB + d);
    ax += v.x;
    ay += v.y;
  }
  float inv = 1.0f / fmaxf((float)(end - beg), 1.0f);
  float2 o = make_float2(ax * inv, ay * inv);
  *reinterpret_cast<float2*>(agg + (long long)node * EMB + d) = o;
}

// ---------------- node GEMM: out = [relu](agg @ Wl + bl + x @ Wr) ----------------
// 32 nodes per 256-thread block. agg is already mean-scaled.
// POOL: instead of writing h, atomically accumulate graph mean-sum / max.
template <bool RELU, bool POOL>
__global__ __launch_bounds__(256) void node_kernel(
    const float* __restrict__ agg, const float* __restrict__ x,
    const float* __restrict__ Wl, const float* __restrict__ bl,
    const float* __restrict__ Wr, const int* __restrict__ batch,
    float* __restrict__ hout, float* __restrict__ gsum,
    unsigned* __restrict__ gmax) {
  __shared__ float sA[32][EMB];
  __shared__ float sX[32][EMB];
  int t = threadIdx.x;
  int base = blockIdx.x * 32;  // N_NODES % 32 == 0
  for (int i = t; i < 32 * EMB / 4; i += 256) {
    int n = i >> 5;
    int c = (i & 31) * 4;
    *reinterpret_cast<float4*>(&sA[n][c]) =
        *reinterpret_cast<const float4*>(agg + (long long)(base + n) * EMB + c);
    *reinterpret_cast<float4*>(&sX[n][c]) =
        *reinterpret_cast<const float4*>(x + (long long)(base + n) * EMB + c);
  }
  __syncthreads();

  int tx = t & 31, ty = t >> 5;
  int d0 = tx * 4;
  float acc[4][4];
#pragma unroll
  for (int a = 0; a < 4; a++)
#pragma unroll
    for (int b = 0; b < 4; b++) acc[a][b] = 0.0f;

  for (int k = 0; k < EMB; k++) {
    float4 wl = *reinterpret_cast<const float4*>(Wl + k * EMB + d0);
    float4 wr = *reinterpret_cast<const float4*>(Wr + k * EMB + d0);
#pragma unroll
    for (int nn = 0; nn < 4; nn++) {
      float av = sA[ty * 4 + nn][k];
      float xv = sX[ty * 4 + nn][k];
      acc[nn][0] += av * wl.x + xv * wr.x;
      acc[nn][1] += av * wl.y + xv * wr.y;
      acc[nn][2] += av * wl.z + xv * wr.z;
      acc[nn][3] += av * wl.w + xv * wr.w;
    }
  }

  float4 bias = *reinterpret_cast<const float4*>(bl + d0);
#pragma unroll
  for (int nn = 0; nn < 4; nn++) {
    int node = base + ty * 4 + nn;
    float v0 = acc[nn][0] + bias.x;
    float v1 = acc[nn][1] + bias.y;
    float v2 = acc[nn][2] + bias.z;
    float v3 = acc[nn][3] + bias.w;
    if (RELU) {
      v0 = fmaxf(v0, 0.0f); v1 = fmaxf(v1, 0.0f);
      v2 = fmaxf(v2, 0.0f); v3 = fmaxf(v3, 0.0f);
    }
    if (POOL) {
      int b = batch[node];
      float* gs = gsum + b * EMB + d0;
      atomicAdd(gs + 0, v0); atomicAdd(gs + 1, v1);
      atomicAdd(gs + 2, v2); atomicAdd(gs + 3, v3);
      unsigned* gm = gmax + b * EMB + d0;
      atomicMax(gm + 0, fkey(v0)); atomicMax(gm + 1, fkey(v1));
      atomicMax(gm + 2, fkey(v2)); atomicMax(gm + 3, fkey(v3));
    } else {
      *reinterpret_cast<float4*>(hout + (long long)node * EMB + d0) =
          make_float4(v0, v1, v2, v3);
    }
  }
}

__global__ void gcnt_kernel(const int* __restrict__ batch,
                            float* __restrict__ gcnt) {
  int i = blockIdx.x * blockDim.x + threadIdx.x;
  if (i < N_NODES) atomicAdd(gcnt + batch[i], 1.0f);
}

// One block per graph, 128 threads = one per embedding dim.
__global__ __launch_bounds__(128) void readout_kernel(
    const float* __restrict__ gsum, const unsigned* __restrict__ gmax,
    const float* __restrict__ gcnt, const float* __restrict__ gfeat,
    const float* __restrict__ Wg, const float* __restrict__ bg,
    const float* __restrict__ Wo, const float* __restrict__ bo,
    float* __restrict__ out) {
  int g = blockIdx.x, d = threadIdx.x;
  float mean = gsum[g * EMB + d] / fmaxf(gcnt[g], 1.0f);
  float mx = fkey_inv(gmax[g * EMB + d]);
  float gfe = bg[d];
#pragma unroll
  for (int k = 0; k < G_FEAT; k++) gfe += gfeat[g * G_FEAT + k] * Wg[k * EMB + d];
  float l0 = mean * Wo[d * 2 + 0] + mx * Wo[(EMB + d) * 2 + 0] +
             gfe * Wo[(2 * EMB + d) * 2 + 0];
  float l1 = mean * Wo[d * 2 + 1] + mx * Wo[(EMB + d) * 2 + 1] +
             gfe * Wo[(2 * EMB + d) * 2 + 1];
  __shared__ float s0[128], s1[128];
  s0[d] = l0; s1[d] = l1;
  __syncthreads();
  for (int off = 64; off > 0; off >>= 1) {
    if (d < off) { s0[d] += s0[d + off]; s1[d] += s1[d + off]; }
    __syncthreads();
  }
  if (d == 0) {
    float a = s0[0] + bo[0];
    float b = s1[0] + bo[1];
    float m = fmaxf(a, b);
    float lse = m + logf(expf(a - m) + expf(b - m));
    out[g * 2 + 0] = a - lse;
    out[g * 2 + 1] = b - lse;
  }
}

extern "C" void kernel_launch(void* const* d_in, const int* in_sizes, int n_in,
                              void* d_out, int out_size, void* d_ws,
                              size_t ws_size, hipStream_t stream) {
  const float* x     = (const float*)d_in[0];
  const int*   edges = (const int*)d_in[1];
  const int*   batch = (const int*)d_in[2];
  const float* gfeat = (const float*)d_in[3];
  const float* W_l0  = (const float*)d_in[4];
  const float* b_l0  = (const float*)d_in[5];
  const float* W_r0  = (const float*)d_in[6];
  const float* W_l1  = (const float*)d_in[7];
  const float* b_l1  = (const float*)d_in[8];
  const float* W_r1  = (const float*)d_in[9];
  const float* W_g   = (const float*)d_in[10];
  const float* b_g   = (const float*)d_in[11];
  const float* W_o   = (const float*)d_in[12];
  const float* b_o   = (const float*)d_in[13];
  const int* srci = edges;
  const int* tgti = edges + N_EDGESC;

  // Workspace layout (zeroed region first):
  // [deg | cursor | gsum | gmax | gcnt] [rowstart | partial | blocksum | ebuf | agg | h]
  char* ws = (char*)d_ws;
  int*      deg      = (int*)ws;                          // N
  int*      cursor   = deg + N_NODES;                     // N
  float*    gsum     = (float*)(cursor + N_NODES);        // 128*128
  unsigned* gmax     = (unsigned*)(gsum + N_GRAPHS * EMB);// 128*128
  float*    gcnt     = (float*)(gmax + N_GRAPHS * EMB);   // 128
  int*      rowstart = (int*)(gcnt + N_GRAPHS);           // N+1
  int*      partial  = rowstart + N_NODES + 1;            // N
  int*      blocksum = partial + N_NODES;                 // SCAN_NBLK (pad 128)
  int*      ebuf     = blocksum + 128;                    // E
  float*    agg      = (float*)(ebuf + N_EDGESC);         // N*128
  float*    h        = agg + (size_t)N_NODES * EMB;       // N*128

  size_t zbytes = (size_t)((char*)rowstart - ws);
  hipMemsetAsync(d_ws, 0, zbytes, stream);

  dim3 b256(256);
  int egrid = (N_EDGESC + 255) / 256;

  // CSR build (once; shared by both layers)
  hist_kernel<<<egrid, b256, 0, stream>>>(tgti, deg);
  scan1_kernel<<<SCAN_NBLK, b256, 0, stream>>>(deg, partial, blocksum);
  scan2_kernel<<<1, 128, 0, stream>>>(blocksum);
  scan3_kernel<<<(N_NODES + 255) / 256, b256, 0, stream>>>(partial, blocksum,
                                                           rowstart);
  fill_kernel<<<egrid, b256, 0, stream>>>(srci, tgti, rowstart, cursor, ebuf);
  gcnt_kernel<<<(N_NODES + 255) / 256, b256, 0, stream>>>(batch, gcnt);

  // Layer 0
  agg_kernel<<<N_NODES / 4, b256, 0, stream>>>(x, ebuf, rowstart, agg);
  node_kernel<true, false><<<N_NODES / 32, b256, 0, stream>>>(
      agg, x, W_l0, b_l0, W_r0, nullptr, h, nullptr, nullptr);

  // Layer 1
  agg_kernel<<<N_NODES / 4, b256, 0, stream>>>(h, ebuf, rowstart, agg);
  node_kernel<false, true><<<N_NODES / 32, b256, 0, stream>>>(
      agg, h, W_l1, b_l1, W_r1, batch, nullptr, gsum, gmax);

  // Readout
  readout_kernel<<<N_GRAPHS, 128, 0, stream>>>(gsum, gmax, gcnt, gfeat, W_g,
                                               b_g, W_o, b_o, (float*)d_out);
}

// Round 4
// 985.407 us; speedup vs baseline: 6.7659x; 1.8131x over previous
//
#include <hip/hip_runtime.h>

// Problem constants (match reference file)
#define N_NODES  100000
#define N_EDGESC 1600000
#define EMB      128
#define N_GRAPHS 128
#define G_FEAT   32
#define SCAN_CHUNK 1024
#define SCAN_NBLK  ((N_NODES + SCAN_CHUNK - 1) / SCAN_CHUNK)  // 98

typedef __attribute__((ext_vector_type(8))) short bf16x8;
typedef __attribute__((ext_vector_type(4))) float f32x4;

// Order-preserving float -> uint key for atomicMax-based float max.
__device__ __forceinline__ unsigned fkey(float f) {
  unsigned u = __float_as_uint(f);
  return (u & 0x80000000u) ? ~u : (u | 0x80000000u);
}
__device__ __forceinline__ float fkey_inv(unsigned k) {
  return (k & 0x80000000u) ? __uint_as_float(k & 0x7FFFFFFFu)
                           : __uint_as_float(~k);
}
__device__ __forceinline__ float bf2f(unsigned short u) {
  return __uint_as_float(((unsigned)u) << 16);
}
__device__ __forceinline__ unsigned short f2bf(float f) {  // RNE
  unsigned u = __float_as_uint(f);
  u += 0x7fffu + ((u >> 16) & 1u);
  return (unsigned short)(u >> 16);
}

// ---------------- dtype conversion / weight packing ----------------

__global__ __launch_bounds__(256) void f2bf_kernel(const float* __restrict__ in,
                                                   unsigned short* __restrict__ out,
                                                   int n4) {
  int i = blockIdx.x * blockDim.x + threadIdx.x;
  if (i >= n4) return;
  float4 v = reinterpret_cast<const float4*>(in)[i];
  uint2 o;
  o.x = (unsigned)f2bf(v.x) | ((unsigned)f2bf(v.y) << 16);
  o.y = (unsigned)f2bf(v.z) | ((unsigned)f2bf(v.w) << 16);
  reinterpret_cast<uint2*>(out)[i] = o;
}

// Pack stacked weights [Wl(128x128); Wr(128x128)] -> MFMA B-fragment order:
// pack[((cb*8+kb)*64+lane)*8 + j] = W[k = kb*32+(lane>>4)*8+j][col = cb*16+(lane&15)]
__global__ __launch_bounds__(256) void pack_kernel(const float* __restrict__ Wl,
                                                   const float* __restrict__ Wr,
                                                   unsigned short* __restrict__ pack) {
  int id = blockIdx.x * blockDim.x + threadIdx.x;
  if (id >= 4096) return;
  int lane = id & 63;
  int kb = (id >> 6) & 7;
  int cb = id >> 9;
  int col = cb * 16 + (lane & 15);
  int k0 = kb * 32 + (lane >> 4) * 8;
  unsigned short v[8];
#pragma unroll
  for (int j = 0; j < 8; j++) {
    int k = k0 + j;
    float w = (k < 128) ? Wl[k * 128 + col] : Wr[(k - 128) * 128 + col];
    v[j] = f2bf(w);
  }
  uint4 o;
  o.x = (unsigned)v[0] | ((unsigned)v[1] << 16);
  o.y = (unsigned)v[2] | ((unsigned)v[3] << 16);
  o.z = (unsigned)v[4] | ((unsigned)v[5] << 16);
  o.w = (unsigned)v[6] | ((unsigned)v[7] << 16);
  *reinterpret_cast<uint4*>(pack + (size_t)id * 8) = o;
}

// ---------------- CSR build ----------------

__global__ void hist_kernel(const int* __restrict__ tgti, int* __restrict__ deg) {
  int e = blockIdx.x * blockDim.x + threadIdx.x;
  if (e < N_EDGESC) atomicAdd(&deg[tgti[e]], 1);
}

__global__ __launch_bounds__(256) void scan1_kernel(const int* __restrict__ deg,
                                                    int* __restrict__ partial,
                                                    int* __restrict__ blocksum) {
  __shared__ int sh[256];
  int t = threadIdx.x;
  int idx0 = blockIdx.x * SCAN_CHUNK + t * 4;
  int v[4], s = 0;
#pragma unroll
  for (int i = 0; i < 4; i++) {
    int idx = idx0 + i;
    v[i] = (idx < N_NODES) ? deg[idx] : 0;
    s += v[i];
  }
  sh[t] = s;
  __syncthreads();
  for (int off = 1; off < 256; off <<= 1) {
    int val = (t >= off) ? sh[t - off] : 0;
    __syncthreads();
    if (t >= off) sh[t] += val;
    __syncthreads();
  }
  int run = sh[t] - s;
#pragma unroll
  for (int i = 0; i < 4; i++) {
    int idx = idx0 + i;
    if (idx < N_NODES) partial[idx] = run;
    run += v[i];
  }
  if (t == 255) blocksum[blockIdx.x] = sh[255];
}

__global__ __launch_bounds__(128) void scan2_kernel(int* __restrict__ blocksum) {
  __shared__ int sh[128];
  int t = threadIdx.x;
  int v = (t < SCAN_NBLK) ? blocksum[t] : 0;
  sh[t] = v;
  __syncthreads();
  for (int off = 1; off < 128; off <<= 1) {
    int val = (t >= off) ? sh[t - off] : 0;
    __syncthreads();
    if (t >= off) sh[t] += val;
    __syncthreads();
  }
  if (t < SCAN_NBLK) blocksum[t] = sh[t] - v;
}

__global__ void scan3_kernel(const int* __restrict__ partial,
                             const int* __restrict__ blocksum,
                             int* __restrict__ rowstart) {
  int i = blockIdx.x * blockDim.x + threadIdx.x;
  if (i < N_NODES) rowstart[i] = partial[i] + blocksum[i / SCAN_CHUNK];
  if (i == 0) rowstart[N_NODES] = N_EDGESC;
}

__global__ void fill_kernel(const int* __restrict__ srci,
                            const int* __restrict__ tgti,
                            const int* __restrict__ rowstart,
                            int* __restrict__ cursor, int* __restrict__ ebuf) {
  int e = blockIdx.x * blockDim.x + threadIdx.x;
  if (e >= N_EDGESC) return;
  int t = tgti[e];
  int pos = atomicAdd(&cursor[t], 1);
  ebuf[rowstart[t] + pos] = srci[e];
}

// ---------------- mean aggregation (bf16 gather, no atomics) ----------------
// One wave per node; lane l owns dims 2l, 2l+1 (one uint = 2 bf16 per lane).
__global__ __launch_bounds__(256) void aggb_kernel(const unsigned short* __restrict__ featB,
                                                   const int* __restrict__ ebuf,
                                                   const int* __restrict__ rowstart,
                                                   unsigned short* __restrict__ aggB) {
  int node = (blockIdx.x * 256 + threadIdx.x) >> 6;
  if (node >= N_NODES) return;
  int lane = threadIdx.x & 63;
  int beg = rowstart[node], end = rowstart[node + 1];
  int off = lane * 2;
  float ax = 0.0f, ay = 0.0f;
  for (int j = beg; j < end; j++) {
    int s = ebuf[j];  // wave-uniform -> broadcast
    unsigned u = *reinterpret_cast<const unsigned*>(featB + (size_t)s * EMB + off);
    ax += bf2f((unsigned short)(u & 0xffffu));
    ay += bf2f((unsigned short)(u >> 16));
  }
  float inv = 1.0f / fmaxf((float)(end - beg), 1.0f);
  unsigned o = (unsigned)f2bf(ax * inv) | ((unsigned)f2bf(ay * inv) << 16);
  *reinterpret_cast<unsigned*>(aggB + (size_t)node * EMB + off) = o;
}

// ---------------- node GEMM via MFMA: out = [relu]([agg|x] @ [Wl;Wr] + bl) ----
// 64 nodes/block, 4 waves x 16 rows. A-frags direct from global; B from pack.
// POOL: stage to LDS, segment-reduce per column (batch_idx sorted), few atomics.
template <bool RELU, bool POOL>
__global__ __launch_bounds__(256) void nodeMM_kernel(
    const unsigned short* __restrict__ aggB, const unsigned short* __restrict__ xB,
    const unsigned short* __restrict__ pack, const float* __restrict__ bl,
    const int* __restrict__ batch, unsigned short* __restrict__ hout,
    float* __restrict__ gsum, unsigned* __restrict__ gmax) {
  int w = threadIdx.x >> 6;
  int lane = threadIdx.x & 63;
  int wbase = blockIdx.x * 64 + w * 16;
  bool active = (wbase < N_NODES);  // N_NODES % 16 == 0 -> whole wave valid

  f32x4 acc[8];
  if (active) {
    bf16x8 afrag[8];
    int row = wbase + (lane & 15);
    int koff = (lane >> 4) * 8;
    const unsigned short* ap = aggB + (size_t)row * EMB + koff;
    const unsigned short* xp = xB + (size_t)row * EMB + koff;
#pragma unroll
    for (int kb = 0; kb < 4; kb++) afrag[kb] = *reinterpret_cast<const bf16x8*>(ap + kb * 32);
#pragma unroll
    for (int kb = 0; kb < 4; kb++) afrag[4 + kb] = *reinterpret_cast<const bf16x8*>(xp + kb * 32);
#pragma unroll
    for (int cb = 0; cb < 8; cb++) {
      f32x4 a = {0.0f, 0.0f, 0.0f, 0.0f};
#pragma unroll
      for (int kb = 0; kb < 8; kb++) {
        bf16x8 b = *reinterpret_cast<const bf16x8*>(pack + ((size_t)(cb * 8 + kb) * 64 + lane) * 8);
        a = __builtin_amdgcn_mfma_f32_16x16x32_bf16(afrag[kb], b, a, 0, 0, 0);
      }
      acc[cb] = a;
    }
  }

  if constexpr (!POOL) {
    if (active) {
#pragma unroll
      for (int cb = 0; cb < 8; cb++) {
        int col = cb * 16 + (lane & 15);
        float bias = bl[col];
#pragma unroll
        for (int r = 0; r < 4; r++) {
          float v = acc[cb][r] + bias;
          if (RELU) v = fmaxf(v, 0.0f);
          int rowl = (lane >> 4) * 4 + r;  // C/D: col=lane&15, row=(lane>>4)*4+r
          hout[(size_t)(wbase + rowl) * EMB + col] = f2bf(v);
        }
      }
    }
  } else {
    __shared__ float sh[64][130];
    __shared__ int sBatch[64];
    if (threadIdx.x < 64) {
      int node = blockIdx.x * 64 + threadIdx.x;
      sBatch[threadIdx.x] = batch[node < N_NODES ? node : (N_NODES - 1)];
    }
    if (active) {
#pragma unroll
      for (int cb = 0; cb < 8; cb++) {
        int col = cb * 16 + (lane & 15);
        float bias = bl[col];
#pragma unroll
        for (int r = 0; r < 4; r++) {
          float v = acc[cb][r] + bias;
          if (RELU) v = fmaxf(v, 0.0f);
          sh[w * 16 + (lane >> 4) * 4 + r][col] = v;
        }
      }
    }
    __syncthreads();
    // Segment reduction: thread t owns column (t&127), rows half*32..+31.
    int col = threadIdx.x & 127;
    int half = threadIdx.x >> 7;
    int nbase = blockIdx.x * 64 + half * 32;
    float rs = 0.0f, rm = -INFINITY;
    int cur = -1;
    for (int r = 0; r < 32; r++) {
      if (nbase + r >= N_NODES) break;
      int b = sBatch[half * 32 + r];
      float v = sh[half * 32 + r][col];
      if (b != cur) {
        if (cur >= 0) {
          atomicAdd(&gsum[cur * EMB + col], rs);
          atomicMax(&gmax[cur * EMB + col], fkey(rm));
        }
        cur = b; rs = 0.0f; rm = -INFINITY;
      }
      rs += v;
      rm = fmaxf(rm, v);
    }
    if (cur >= 0) {
      atomicAdd(&gsum[cur * EMB + col], rs);
      atomicMax(&gmax[cur * EMB + col], fkey(rm));
    }
  }
}

__global__ void gcnt_kernel(const int* __restrict__ batch,
                            float* __restrict__ gcnt) {
  int i = blockIdx.x * blockDim.x + threadIdx.x;
  if (i < N_NODES) atomicAdd(gcnt + batch[i], 1.0f);
}

// One block per graph, 128 threads = one per embedding dim.
__global__ __launch_bounds__(128) void readout_kernel(
    const float* __restrict__ gsum, const unsigned* __restrict__ gmax,
    const float* __restrict__ gcnt, const float* __restrict__ gfeat,
    const float* __restrict__ Wg, const float* __restrict__ bg,
    const float* __restrict__ Wo, const float* __restrict__ bo,
    float* __restrict__ out) {
  int g = blockIdx.x, d = threadIdx.x;
  float mean = gsum[g * EMB + d] / fmaxf(gcnt[g], 1.0f);
  float mx = fkey_inv(gmax[g * EMB + d]);
  float gfe = bg[d];
#pragma unroll
  for (int k = 0; k < G_FEAT; k++) gfe += gfeat[g * G_FEAT + k] * Wg[k * EMB + d];
  float l0 = mean * Wo[d * 2 + 0] + mx * Wo[(EMB + d) * 2 + 0] +
             gfe * Wo[(2 * EMB + d) * 2 + 0];
  float l1 = mean * Wo[d * 2 + 1] + mx * Wo[(EMB + d) * 2 + 1] +
             gfe * Wo[(2 * EMB + d) * 2 + 1];
  __shared__ float s0[128], s1[128];
  s0[d] = l0; s1[d] = l1;
  __syncthreads();
  for (int off = 64; off > 0; off >>= 1) {
    if (d < off) { s0[d] += s0[d + off]; s1[d] += s1[d + off]; }
    __syncthreads();
  }
  if (d == 0) {
    float a = s0[0] + bo[0];
    float b = s1[0] + bo[1];
    float m = fmaxf(a, b);
    float lse = m + logf(expf(a - m) + expf(b - m));
    out[g * 2 + 0] = a - lse;
    out[g * 2 + 1] = b - lse;
  }
}

extern "C" void kernel_launch(void* const* d_in, const int* in_sizes, int n_in,
                              void* d_out, int out_size, void* d_ws,
                              size_t ws_size, hipStream_t stream) {
  const float* x     = (const float*)d_in[0];
  const int*   edges = (const int*)d_in[1];
  const int*   batch = (const int*)d_in[2];
  const float* gfeat = (const float*)d_in[3];
  const float* W_l0  = (const float*)d_in[4];
  const float* b_l0  = (const float*)d_in[5];
  const float* W_r0  = (const float*)d_in[6];
  const float* W_l1  = (const float*)d_in[7];
  const float* b_l1  = (const float*)d_in[8];
  const float* W_r1  = (const float*)d_in[9];
  const float* W_g   = (const float*)d_in[10];
  const float* b_g   = (const float*)d_in[11];
  const float* W_o   = (const float*)d_in[12];
  const float* b_o   = (const float*)d_in[13];
  const int* srci = edges;
  const int* tgti = edges + N_EDGESC;

  // Workspace layout. Zeroed region first: [deg | cursor | gsum | gmax | gcnt]
  char* ws = (char*)d_ws;
  int*      deg      = (int*)ws;                            // N
  int*      cursor   = deg + N_NODES;                       // N
  float*    gsum     = (float*)(cursor + N_NODES);          // 128*128
  unsigned* gmax     = (unsigned*)(gsum + N_GRAPHS * EMB);  // 128*128
  float*    gcnt     = (float*)(gmax + N_GRAPHS * EMB);     // 128
  unsigned short* xB   = (unsigned short*)(gcnt + N_GRAPHS);      // N*128 bf16
  unsigned short* aggB = xB + (size_t)N_NODES * EMB;              // N*128 bf16
  unsigned short* hB   = aggB + (size_t)N_NODES * EMB;            // N*128 bf16
  unsigned short* pack0 = hB + (size_t)N_NODES * EMB;             // 32768 bf16
  unsigned short* pack1 = pack0 + 8 * 8 * 64 * 8;                 // 32768 bf16
  int*      ebuf     = (int*)(pack1 + 8 * 8 * 64 * 8);      // E
  int*      rowstart = ebuf + N_EDGESC;                     // N+1
  int*      partial  = rowstart + N_NODES + 1;              // N
  int*      blocksum = partial + N_NODES;                   // pad 128

  size_t zbytes = (size_t)((char*)xB - ws);
  hipMemsetAsync(d_ws, 0, zbytes, stream);

  dim3 b256(256);
  int egrid = (N_EDGESC + 255) / 256;

  // Conversions / packing (small)
  f2bf_kernel<<<(N_NODES * EMB / 4 + 255) / 256, b256, 0, stream>>>(x, xB,
                                                                    N_NODES * EMB / 4);
  pack_kernel<<<16, b256, 0, stream>>>(W_l0, W_r0, pack0);
  pack_kernel<<<16, b256, 0, stream>>>(W_l1, W_r1, pack1);

  // CSR build (shared by both layers)
  hist_kernel<<<egrid, b256, 0, stream>>>(tgti, deg);
  scan1_kernel<<<SCAN_NBLK, b256, 0, stream>>>(deg, partial, blocksum);
  scan2_kernel<<<1, 128, 0, stream>>>(blocksum);
  scan3_kernel<<<(N_NODES + 255) / 256, b256, 0, stream>>>(partial, blocksum,
                                                           rowstart);
  fill_kernel<<<egrid, b256, 0, stream>>>(srci, tgti, rowstart, cursor, ebuf);
  gcnt_kernel<<<(N_NODES + 255) / 256, b256, 0, stream>>>(batch, gcnt);

  int ngrid = (N_NODES + 63) / 64;  // 1563

  // Layer 0
  aggb_kernel<<<N_NODES / 4, b256, 0, stream>>>(xB, ebuf, rowstart, aggB);
  nodeMM_kernel<true, false><<<ngrid, b256, 0, stream>>>(
      aggB, xB, pack0, b_l0, nullptr, hB, nullptr, nullptr);

  // Layer 1
  aggb_kernel<<<N_NODES / 4, b256, 0, stream>>>(hB, ebuf, rowstart, aggB);
  nodeMM_kernel<false, true><<<ngrid, b256, 0, stream>>>(
      aggB, hB, pack1, b_l1, batch, nullptr, gsum, gmax);

  // Readout
  readout_kernel<<<N_GRAPHS, 128, 0, stream>>>(gsum, gmax, gcnt, gfeat, W_g,
                                               b_g, W_o, b_o, (float*)d_out);
}

// Round 6
// 642.744 us; speedup vs baseline: 10.3729x; 1.5331x over previous
//
#include <hip/hip_runtime.h>

// Problem constants (match reference file)
#define N_NODES  100000
#define N_EDGESC 1600000
#define EMB      128
#define N_GRAPHS 128
#define G_FEAT   32
#define SCAN_CHUNK 1024
#define SCAN_NBLK  ((N_NODES + SCAN_CHUNK - 1) / SCAN_CHUNK)  // 98

typedef __attribute__((ext_vector_type(8))) short bf16x8;
typedef __attribute__((ext_vector_type(4))) float f32x4;

// Order-preserving float -> uint key for atomicMax-based float max.
__device__ __forceinline__ unsigned fkey(float f) {
  unsigned u = __float_as_uint(f);
  return (u & 0x80000000u) ? ~u : (u | 0x80000000u);
}
__device__ __forceinline__ float fkey_inv(unsigned k) {
  return (k & 0x80000000u) ? __uint_as_float(k & 0x7FFFFFFFu)
                           : __uint_as_float(~k);
}
__device__ __forceinline__ float bf2f(unsigned short u) {
  return __uint_as_float(((unsigned)u) << 16);
}
__device__ __forceinline__ unsigned short f2bf(float f) {  // RNE
  unsigned u = __float_as_uint(f);
  u += 0x7fffu + ((u >> 16) & 1u);
  return (unsigned short)(u >> 16);
}

// ---------------- dtype conversion / weight packing ----------------

__global__ __launch_bounds__(256) void f2bf_kernel(const float* __restrict__ in,
                                                   unsigned short* __restrict__ out,
                                                   int n4) {
  int i = blockIdx.x * blockDim.x + threadIdx.x;
  if (i >= n4) return;
  float4 v = reinterpret_cast<const float4*>(in)[i];
  uint2 o;
  o.x = (unsigned)f2bf(v.x) | ((unsigned)f2bf(v.y) << 16);
  o.y = (unsigned)f2bf(v.z) | ((unsigned)f2bf(v.w) << 16);
  reinterpret_cast<uint2*>(out)[i] = o;
}

// Pack stacked weights [Wl(128x128); Wr(128x128)] -> MFMA B-fragment order:
// pack[((cb*8+kb)*64+lane)*8 + j] = W[k = kb*32+(lane>>4)*8+j][col = cb*16+(lane&15)]
__global__ __launch_bounds__(256) void pack_kernel(const float* __restrict__ Wl,
                                                   const float* __restrict__ Wr,
                                                   unsigned short* __restrict__ pack) {
  int id = blockIdx.x * blockDim.x + threadIdx.x;
  if (id >= 4096) return;
  int lane = id & 63;
  int kb = (id >> 6) & 7;
  int cb = id >> 9;
  int col = cb * 16 + (lane & 15);
  int k0 = kb * 32 + (lane >> 4) * 8;
  unsigned short v[8];
#pragma unroll
  for (int j = 0; j < 8; j++) {
    int k = k0 + j;
    float w = (k < 128) ? Wl[k * 128 + col] : Wr[(k - 128) * 128 + col];
    v[j] = f2bf(w);
  }
  uint4 o;
  o.x = (unsigned)v[0] | ((unsigned)v[1] << 16);
  o.y = (unsigned)v[2] | ((unsigned)v[3] << 16);
  o.z = (unsigned)v[4] | ((unsigned)v[5] << 16);
  o.w = (unsigned)v[6] | ((unsigned)v[7] << 16);
  *reinterpret_cast<uint4*>(pack + (size_t)id * 8) = o;
}

// ---------------- CSR build ----------------

__global__ void hist_kernel(const int* __restrict__ tgti, int* __restrict__ deg) {
  int e = blockIdx.x * blockDim.x + threadIdx.x;
  if (e < N_EDGESC) atomicAdd(&deg[tgti[e]], 1);
}

__global__ __launch_bounds__(256) void scan1_kernel(const int* __restrict__ deg,
                                                    int* __restrict__ partial,
                                                    int* __restrict__ blocksum) {
  __shared__ int sh[256];
  int t = threadIdx.x;
  int idx0 = blockIdx.x * SCAN_CHUNK + t * 4;
  int v[4], s = 0;
#pragma unroll
  for (int i = 0; i < 4; i++) {
    int idx = idx0 + i;
    v[i] = (idx < N_NODES) ? deg[idx] : 0;
    s += v[i];
  }
  sh[t] = s;
  __syncthreads();
  for (int off = 1; off < 256; off <<= 1) {
    int val = (t >= off) ? sh[t - off] : 0;
    __syncthreads();
    if (t >= off) sh[t] += val;
    __syncthreads();
  }
  int run = sh[t] - s;
#pragma unroll
  for (int i = 0; i < 4; i++) {
    int idx = idx0 + i;
    if (idx < N_NODES) partial[idx] = run;
    run += v[i];
  }
  if (t == 255) blocksum[blockIdx.x] = sh[255];
}

__global__ __launch_bounds__(128) void scan2_kernel(int* __restrict__ blocksum) {
  __shared__ int sh[128];
  int t = threadIdx.x;
  int v = (t < SCAN_NBLK) ? blocksum[t] : 0;
  sh[t] = v;
  __syncthreads();
  for (int off = 1; off < 128; off <<= 1) {
    int val = (t >= off) ? sh[t - off] : 0;
    __syncthreads();
    if (t >= off) sh[t] += val;
    __syncthreads();
  }
  if (t < SCAN_NBLK) blocksum[t] = sh[t] - v;
}

__global__ void scan3_kernel(const int* __restrict__ partial,
                             const int* __restrict__ blocksum,
                             int* __restrict__ rowstart) {
  int i = blockIdx.x * blockDim.x + threadIdx.x;
  if (i < N_NODES) rowstart[i] = partial[i] + blocksum[i / SCAN_CHUNK];
  if (i == 0) rowstart[N_NODES] = N_EDGESC;
}

__global__ void fill_kernel(const int* __restrict__ srci,
                            const int* __restrict__ tgti,
                            const int* __restrict__ rowstart,
                             int* __restrict__ cursor, int* __restrict__ ebuf) {
  int e = blockIdx.x * blockDim.x + threadIdx.x;
  if (e >= N_EDGESC) return;
  int t = tgti[e];
  int pos = atomicAdd(&cursor[t], 1);
  ebuf[rowstart[t] + pos] = srci[e];
}

// ---------------- mean aggregation (bf16 gather, no atomics) ----------------
// One wave per node; lane l owns dims 2l, 2l+1 (one uint = 2 bf16 per lane).
__global__ __launch_bounds__(256) void aggb_kernel(const unsigned short* __restrict__ featB,
                                                   const int* __restrict__ ebuf,
                                                   const int* __restrict__ rowstart,
                                                   unsigned short* __restrict__ aggB) {
  int node = (blockIdx.x * 256 + threadIdx.x) >> 6;
  if (node >= N_NODES) return;
  int lane = threadIdx.x & 63;
  int beg = rowstart[node], end = rowstart[node + 1];
  int off = lane * 2;
  float ax = 0.0f, ay = 0.0f;
  for (int j = beg; j < end; j++) {
    int s = ebuf[j];  // wave-uniform -> broadcast
    unsigned u = *reinterpret_cast<const unsigned*>(featB + (size_t)s * EMB + off);
    ax += bf2f((unsigned short)(u & 0xffffu));
    ay += bf2f((unsigned short)(u >> 16));
  }
  float inv = 1.0f / fmaxf((float)(end - beg), 1.0f);
  unsigned o = (unsigned)f2bf(ax * inv) | ((unsigned)f2bf(ay * inv) << 16);
  *reinterpret_cast<unsigned*>(aggB + (size_t)node * EMB + off) = o;
}

// ---------------- node GEMM via MFMA: out = [relu]([agg|x] @ [Wl;Wr] + bl) ----
// 64 nodes/block, 4 waves x 16 rows. A-frags direct from global; B from pack.
// POOL: stage to LDS, segment-reduce per column (batch_idx sorted), few atomics.
template <bool RELU, bool POOL>
__global__ __launch_bounds__(256) void nodeMM_kernel(
    const unsigned short* __restrict__ aggB, const unsigned short* __restrict__ xB,
    const unsigned short* __restrict__ pack, const float* __restrict__ bl,
    const int* __restrict__ batch, unsigned short* __restrict__ hout,
    float* __restrict__ gsum, unsigned* __restrict__ gmax) {
  int w = threadIdx.x >> 6;
  int lane = threadIdx.x & 63;
  int wbase = blockIdx.x * 64 + w * 16;
  bool active = (wbase < N_NODES);  // N_NODES % 16 == 0 -> whole wave valid

  f32x4 acc[8];
  if (active) {
    bf16x8 afrag[8];
    int row = wbase + (lane & 15);
    int koff = (lane >> 4) * 8;
    const unsigned short* ap = aggB + (size_t)row * EMB + koff;
    const unsigned short* xp = xB + (size_t)row * EMB + koff;
#pragma unroll
    for (int kb = 0; kb < 4; kb++) afrag[kb] = *reinterpret_cast<const bf16x8*>(ap + kb * 32);
#pragma unroll
    for (int kb = 0; kb < 4; kb++) afrag[4 + kb] = *reinterpret_cast<const bf16x8*>(xp + kb * 32);
#pragma unroll
    for (int cb = 0; cb < 8; cb++) {
      f32x4 a = {0.0f, 0.0f, 0.0f, 0.0f};
#pragma unroll
      for (int kb = 0; kb < 8; kb++) {
        bf16x8 b = *reinterpret_cast<const bf16x8*>(pack + ((size_t)(cb * 8 + kb) * 64 + lane) * 8);
        a = __builtin_amdgcn_mfma_f32_16x16x32_bf16(afrag[kb], b, a, 0, 0, 0);
      }
      acc[cb] = a;
    }
  }

  if constexpr (!POOL) {
    if (active) {
#pragma unroll
      for (int cb = 0; cb < 8; cb++) {
        int col = cb * 16 + (lane & 15);
        float bias = bl[col];
#pragma unroll
        for (int r = 0; r < 4; r++) {
          float v = acc[cb][r] + bias;
          if (RELU) v = fmaxf(v, 0.0f);
          int rowl = (lane >> 4) * 4 + r;  // C/D: col=lane&15, row=(lane>>4)*4+r
          hout[(size_t)(wbase + rowl) * EMB + col] = f2bf(v);
        }
      }
    }
  } else {
    __shared__ float sh[64][130];
    __shared__ int sBatch[64];
    if (threadIdx.x < 64) {
      int node = blockIdx.x * 64 + threadIdx.x;
      sBatch[threadIdx.x] = batch[node < N_NODES ? node : (N_NODES - 1)];
    }
    if (active) {
#pragma unroll
      for (int cb = 0; cb < 8; cb++) {
        int col = cb * 16 + (lane & 15);
        float bias = bl[col];
#pragma unroll
        for (int r = 0; r < 4; r++) {
          float v = acc[cb][r] + bias;
          if (RELU) v = fmaxf(v, 0.0f);
          sh[w * 16 + (lane >> 4) * 4 + r][col] = v;
        }
      }
    }
    __syncthreads();
    // Segment reduction: thread t owns column (t&127), rows half*32..+31.
    int col = threadIdx.x & 127;
    int half = threadIdx.x >> 7;
    int nbase = blockIdx.x * 64 + half * 32;
    float rs = 0.0f, rm = -INFINITY;
    int cur = -1;
    for (int r = 0; r < 32; r++) {
      if (nbase + r >= N_NODES) break;
      int b = sBatch[half * 32 + r];
      float v = sh[half * 32 + r][col];
      if (b != cur) {
        if (cur >= 0) {
          atomicAdd(&gsum[cur * EMB + col], rs);
          atomicMax(&gmax[cur * EMB + col], fkey(rm));
        }
        cur = b; rs = 0.0f; rm = -INFINITY;
      }
      rs += v;
      rm = fmaxf(rm, v);
    }
    if (cur >= 0) {
      atomicAdd(&gsum[cur * EMB + col], rs);
      atomicMax(&gmax[cur * EMB + col], fkey(rm));
    }
  }
}

// batch_idx is SORTED -> per-graph counts via binary search, no atomics.
// One block, 128 threads; thread g finds lower_bound(batch, g).
__global__ __launch_bounds__(128) void gcnt_kernel(const int* __restrict__ batch,
                                                   float* __restrict__ gcnt) {
  __shared__ int lb[129];
  int g = threadIdx.x;
  int lo = 0, hi = N_NODES;
  while (lo < hi) {
    int mid = (lo + hi) >> 1;
    if (batch[mid] < g) lo = mid + 1; else hi = mid;
  }
  lb[g] = lo;
  if (g == 0) lb[128] = N_NODES;
  __syncthreads();
  gcnt[g] = (float)(lb[g + 1] - lb[g]);
}

// One block per graph, 128 threads = one per embedding dim.
__global__ __launch_bounds__(128) void readout_kernel(
    const float* __restrict__ gsum, const unsigned* __restrict__ gmax,
    const float* __restrict__ gcnt, const float* __restrict__ gfeat,
    const float* __restrict__ Wg, const float* __restrict__ bg,
    const float* __restrict__ Wo, const float* __restrict__ bo,
    float* __restrict__ out) {
  int g = blockIdx.x, d = threadIdx.x;
  float mean = gsum[g * EMB + d] / fmaxf(gcnt[g], 1.0f);
  float mx = fkey_inv(gmax[g * EMB + d]);
  float gfe = bg[d];
#pragma unroll
  for (int k = 0; k < G_FEAT; k++) gfe += gfeat[g * G_FEAT + k] * Wg[k * EMB + d];
  float l0 = mean * Wo[d * 2 + 0] + mx * Wo[(EMB + d) * 2 + 0] +
             gfe * Wo[(2 * EMB + d) * 2 + 0];
  float l1 = mean * Wo[d * 2 + 1] + mx * Wo[(EMB + d) * 2 + 1] +
             gfe * Wo[(2 * EMB + d) * 2 + 1];
  __shared__ float s0[128], s1[128];
  s0[d] = l0; s1[d] = l1;
  __syncthreads();
  for (int off = 64; off > 0; off >>= 1) {
    if (d < off) { s0[d] += s0[d + off]; s1[d] += s1[d + off]; }
    __syncthreads();
  }
  if (d == 0) {
    float a = s0[0] + bo[0];
    float b = s1[0] + bo[1];
    float m = fmaxf(a, b);
    float lse = m + logf(expf(a - m) + expf(b - m));
    out[g * 2 + 0] = a - lse;
    out[g * 2 + 1] = b - lse;
  }
}

extern "C" void kernel_launch(void* const* d_in, const int* in_sizes, int n_in,
                              void* d_out, int out_size, void* d_ws,
                              size_t ws_size, hipStream_t stream) {
  const float* x     = (const float*)d_in[0];
  const int*   edges = (const int*)d_in[1];
  const int*   batch = (const int*)d_in[2];
  const float* gfeat = (const float*)d_in[3];
  const float* W_l0  = (const float*)d_in[4];
  const float* b_l0  = (const float*)d_in[5];
  const float* W_r0  = (const float*)d_in[6];
  const float* W_l1  = (const float*)d_in[7];
  const float* b_l1  = (const float*)d_in[8];
  const float* W_r1  = (const float*)d_in[9];
  const float* W_g   = (const float*)d_in[10];
  const float* b_g   = (const float*)d_in[11];
  const float* W_o   = (const float*)d_in[12];
  const float* b_o   = (const float*)d_in[13];
  const int* srci = edges;
  const int* tgti = edges + N_EDGESC;

  // Workspace layout. Zeroed region first: [deg | cursor | gsum | gmax | gcnt]
  char* ws = (char*)d_ws;
  int*      deg      = (int*)ws;                            // N
  int*      cursor   = deg + N_NODES;                       // N
  float*    gsum     = (float*)(cursor + N_NODES);          // 128*128
  unsigned* gmax     = (unsigned*)(gsum + N_GRAPHS * EMB);  // 128*128
  float*    gcnt     = (float*)(gmax + N_GRAPHS * EMB);     // 128
  unsigned short* xB   = (unsigned short*)(gcnt + N_GRAPHS);      // N*128 bf16
  unsigned short* aggB = xB + (size_t)N_NODES * EMB;              // N*128 bf16
  unsigned short* hB   = aggB + (size_t)N_NODES * EMB;            // N*128 bf16
  unsigned short* pack0 = hB + (size_t)N_NODES * EMB;             // 32768 bf16
  unsigned short* pack1 = pack0 + 8 * 8 * 64 * 8;                 // 32768 bf16
  int*      ebuf     = (int*)(pack1 + 8 * 8 * 64 * 8);      // E
  int*      rowstart = ebuf + N_EDGESC;                     // N+1
  int*      partial  = rowstart + N_NODES + 1;              // N
  int*      blocksum = partial + N_NODES;                   // pad 128

  size_t zbytes = (size_t)((char*)xB - ws);
  hipMemsetAsync(d_ws, 0, zbytes, stream);

  dim3 b256(256);
  int egrid = (N_EDGESC + 255) / 256;

  // Conversions / packing (small)
  f2bf_kernel<<<(N_NODES * EMB / 4 + 255) / 256, b256, 0, stream>>>(x, xB,
                                                                    N_NODES * EMB / 4);
  pack_kernel<<<16, b256, 0, stream>>>(W_l0, W_r0, pack0);
  pack_kernel<<<16, b256, 0, stream>>>(W_l1, W_r1, pack1);

  // CSR build (shared by both layers)
  hist_kernel<<<egrid, b256, 0, stream>>>(tgti, deg);
  scan1_kernel<<<SCAN_NBLK, b256, 0, stream>>>(deg, partial, blocksum);
  scan2_kernel<<<1, 128, 0, stream>>>(blocksum);
  scan3_kernel<<<(N_NODES + 255) / 256, b256, 0, stream>>>(partial, blocksum,
                                                           rowstart);
  fill_kernel<<<egrid, b256, 0, stream>>>(srci, tgti, rowstart, cursor, ebuf);
  gcnt_kernel<<<1, 128, 0, stream>>>(batch, gcnt);

  int ngrid = (N_NODES + 63) / 64;  // 1563

  // Layer 0
  aggb_kernel<<<N_NODES / 4, b256, 0, stream>>>(xB, ebuf, rowstart, aggB);
  nodeMM_kernel<true, false><<<ngrid, b256, 0, stream>>>(
      aggB, xB, pack0, b_l0, nullptr, hB, nullptr, nullptr);

  // Layer 1
  aggb_kernel<<<N_NODES / 4, b256, 0, stream>>>(hB, ebuf, rowstart, aggB);
  nodeMM_kernel<false, true><<<ngrid, b256, 0, stream>>>(
      aggB, hB, pack1, b_l1, batch, nullptr, gsum, gmax);

  // Readout
  readout_kernel<<<N_GRAPHS, 128, 0, stream>>>(gsum, gmax, gcnt, gfeat, W_g,
                                               b_g, W_o, b_o, (float*)d_out);
}

// Round 8
// 455.960 us; speedup vs baseline: 14.6222x; 1.4096x over previous
//
#include <hip/hip_runtime.h>

// Problem constants (match reference file)
#define N_NODES  100000
#define N_EDGESC 1600000
#define EMB      128
#define N_GRAPHS 128
#define G_FEAT   32
#define SCAN_CHUNK 1024
#define SCAN_NBLK  ((N_NODES + SCAN_CHUNK - 1) / SCAN_CHUNK)  // 98

typedef __attribute__((ext_vector_type(8))) short bf16x8;
typedef __attribute__((ext_vector_type(4))) float f32x4;

// Order-preserving float -> uint key for atomicMax-based float max.
__device__ __forceinline__ unsigned fkey(float f) {
  unsigned u = __float_as_uint(f);
  return (u & 0x80000000u) ? ~u : (u | 0x80000000u);
}
__device__ __forceinline__ float fkey_inv(unsigned k) {
  return (k & 0x80000000u) ? __uint_as_float(k & 0x7FFFFFFFu)
                           : __uint_as_float(~k);
}
__device__ __forceinline__ float bf2f(unsigned short u) {
  return __uint_as_float(((unsigned)u) << 16);
}
__device__ __forceinline__ unsigned short f2bf(float f) {  // RNE
  unsigned u = __float_as_uint(f);
  u += 0x7fffu + ((u >> 16) & 1u);
  return (unsigned short)(u >> 16);
}

// ---------------- dtype conversion / weight packing ----------------

__global__ __launch_bounds__(256) void f2bf_kernel(const float* __restrict__ in,
                                                   unsigned short* __restrict__ out,
                                                   int n4) {
  int i = blockIdx.x * blockDim.x + threadIdx.x;
  if (i >= n4) return;
  float4 v = reinterpret_cast<const float4*>(in)[i];
  uint2 o;
  o.x = (unsigned)f2bf(v.x) | ((unsigned)f2bf(v.y) << 16);
  o.y = (unsigned)f2bf(v.z) | ((unsigned)f2bf(v.w) << 16);
  reinterpret_cast<uint2*>(out)[i] = o;
}

// Pack stacked weights [Wl(128x128); Wr(128x128)] -> MFMA B-fragment order:
// pack[((cb*8+kb)*64+lane)*8 + j] = W[k = kb*32+(lane>>4)*8+j][col = cb*16+(lane&15)]
__global__ __launch_bounds__(256) void pack_kernel(const float* __restrict__ Wl,
                                                   const float* __restrict__ Wr,
                                                   unsigned short* __restrict__ pack) {
  int id = blockIdx.x * blockDim.x + threadIdx.x;
  if (id >= 4096) return;
  int lane = id & 63;
  int kb = (id >> 6) & 7;
  int cb = id >> 9;
  int col = cb * 16 + (lane & 15);
  int k0 = kb * 32 + (lane >> 4) * 8;
  unsigned short v[8];
#pragma unroll
  for (int j = 0; j < 8; j++) {
    int k = k0 + j;
    float w = (k < 128) ? Wl[k * 128 + col] : Wr[(k - 128) * 128 + col];
    v[j] = f2bf(w);
  }
  uint4 o;
  o.x = (unsigned)v[0] | ((unsigned)v[1] << 16);
  o.y = (unsigned)v[2] | ((unsigned)v[3] << 16);
  o.z = (unsigned)v[4] | ((unsigned)v[5] << 16);
  o.w = (unsigned)v[6] | ((unsigned)v[7] << 16);
  *reinterpret_cast<uint4*>(pack + (size_t)id * 8) = o;
}

// ---------------- CSR build ----------------

__global__ void hist_kernel(const int* __restrict__ tgti, int* __restrict__ deg) {
  int e = blockIdx.x * blockDim.x + threadIdx.x;
  if (e < N_EDGESC) atomicAdd(&deg[tgti[e]], 1);
}

__global__ __launch_bounds__(256) void scan1_kernel(const int* __restrict__ deg,
                                                    int* __restrict__ partial,
                                                    int* __restrict__ blocksum) {
  __shared__ int sh[256];
  int t = threadIdx.x;
  int idx0 = blockIdx.x * SCAN_CHUNK + t * 4;
  int v[4], s = 0;
#pragma unroll
  for (int i = 0; i < 4; i++) {
    int idx = idx0 + i;
    v[i] = (idx < N_NODES) ? deg[idx] : 0;
    s += v[i];
  }
  sh[t] = s;
  __syncthreads();
  for (int off = 1; off < 256; off <<= 1) {
    int val = (t >= off) ? sh[t - off] : 0;
    __syncthreads();
    if (t >= off) sh[t] += val;
    __syncthreads();
  }
  int run = sh[t] - s;
#pragma unroll
  for (int i = 0; i < 4; i++) {
    int idx = idx0 + i;
    if (idx < N_NODES) partial[idx] = run;
    run += v[i];
  }
  if (t == 255) blocksum[blockIdx.x] = sh[255];
}

__global__ __launch_bounds__(128) void scan2_kernel(int* __restrict__ blocksum) {
  __shared__ int sh[128];
  int t = threadIdx.x;
  int v = (t < SCAN_NBLK) ? blocksum[t] : 0;
  sh[t] = v;
  __syncthreads();
  for (int off = 1; off < 128; off <<= 1) {
    int val = (t >= off) ? sh[t - off] : 0;
    __syncthreads();
    if (t >= off) sh[t] += val;
    __syncthreads();
  }
  if (t < SCAN_NBLK) blocksum[t] = sh[t] - v;
}

__global__ void scan3_kernel(const int* __restrict__ partial,
                             const int* __restrict__ blocksum,
                             int* __restrict__ rowstart) {
  int i = blockIdx.x * blockDim.x + threadIdx.x;
  if (i < N_NODES) rowstart[i] = partial[i] + blocksum[i / SCAN_CHUNK];
  if (i == 0) rowstart[N_NODES] = N_EDGESC;
}

__global__ void fill_kernel(const int* __restrict__ srci,
                            const int* __restrict__ tgti,
                            const int* __restrict__ rowstart,
                             int* __restrict__ cursor, int* __restrict__ ebuf) {
  int e = blockIdx.x * blockDim.x + threadIdx.x;
  if (e >= N_EDGESC) return;
  int t = tgti[e];
  int pos = atomicAdd(&cursor[t], 1);
  ebuf[rowstart[t] + pos] = srci[e];
}

// ---------------- mean aggregation (bf16 gather, no atomics) ----------------
// 2 nodes per wave: half-wave of 32 lanes per node, lane owns 4 dims (8 B).
// Edge loop unrolled x4 -> 4 independent row gathers in flight (ILP).
__global__ __launch_bounds__(256) void aggb_kernel(const unsigned short* __restrict__ featB,
                                                   const int* __restrict__ ebuf,
                                                   const int* __restrict__ rowstart,
                                                   unsigned short* __restrict__ aggB) {
  int wid = (blockIdx.x * 256 + threadIdx.x) >> 6;  // global wave id
  int lane = threadIdx.x & 63;
  int node = wid * 2 + (lane >> 5);
  if (node >= N_NODES) return;
  int l = lane & 31;
  int beg = rowstart[node], end = rowstart[node + 1];
  int off = l * 4;  // 4 bf16 = 8 B per lane
  float a0 = 0.0f, a1 = 0.0f, a2 = 0.0f, a3 = 0.0f;
  int j = beg;
  for (; j + 4 <= end; j += 4) {
    int s0 = ebuf[j], s1 = ebuf[j + 1], s2 = ebuf[j + 2], s3 = ebuf[j + 3];
    uint2 u0 = *reinterpret_cast<const uint2*>(featB + (size_t)s0 * EMB + off);
    uint2 u1 = *reinterpret_cast<const uint2*>(featB + (size_t)s1 * EMB + off);
    uint2 u2 = *reinterpret_cast<const uint2*>(featB + (size_t)s2 * EMB + off);
    uint2 u3 = *reinterpret_cast<const uint2*>(featB + (size_t)s3 * EMB + off);
    a0 += bf2f((unsigned short)(u0.x & 0xffffu)) + bf2f((unsigned short)(u1.x & 0xffffu)) +
          bf2f((unsigned short)(u2.x & 0xffffu)) + bf2f((unsigned short)(u3.x & 0xffffu));
    a1 += bf2f((unsigned short)(u0.x >> 16)) + bf2f((unsigned short)(u1.x >> 16)) +
          bf2f((unsigned short)(u2.x >> 16)) + bf2f((unsigned short)(u3.x >> 16));
    a2 += bf2f((unsigned short)(u0.y & 0xffffu)) + bf2f((unsigned short)(u1.y & 0xffffu)) +
          bf2f((unsigned short)(u2.y & 0xffffu)) + bf2f((unsigned short)(u3.y & 0xffffu));
    a3 += bf2f((unsigned short)(u0.y >> 16)) + bf2f((unsigned short)(u1.y >> 16)) +
          bf2f((unsigned short)(u2.y >> 16)) + bf2f((unsigned short)(u3.y >> 16));
  }
  for (; j < end; j++) {
    int s = ebuf[j];
    uint2 u = *reinterpret_cast<const uint2*>(featB + (size_t)s * EMB + off);
    a0 += bf2f((unsigned short)(u.x & 0xffffu));
    a1 += bf2f((unsigned short)(u.x >> 16));
    a2 += bf2f((unsigned short)(u.y & 0xffffu));
    a3 += bf2f((unsigned short)(u.y >> 16));
  }
  float inv = 1.0f / fmaxf((float)(end - beg), 1.0f);
  uint2 o;
  o.x = (unsigned)f2bf(a0 * inv) | ((unsigned)f2bf(a1 * inv) << 16);
  o.y = (unsigned)f2bf(a2 * inv) | ((unsigned)f2bf(a3 * inv) << 16);
  *reinterpret_cast<uint2*>(aggB + (size_t)node * EMB + off) = o;
}

// ---------------- node GEMM via MFMA: out = [relu]([agg|x] @ [Wl;Wr] + bl) ----
// 64 nodes/block, 4 waves x 16 rows. A-frags direct from global; B from pack.
// POOL: stage to LDS, segment-reduce per column (batch_idx sorted), few atomics.
template <bool RELU, bool POOL>
__global__ __launch_bounds__(256) void nodeMM_kernel(
    const unsigned short* __restrict__ aggB, const unsigned short* __restrict__ xB,
    const unsigned short* __restrict__ pack, const float* __restrict__ bl,
    const int* __restrict__ batch, unsigned short* __restrict__ hout,
    float* __restrict__ gsum, unsigned* __restrict__ gmax) {
  int w = threadIdx.x >> 6;
  int lane = threadIdx.x & 63;
  int wbase = blockIdx.x * 64 + w * 16;
  bool active = (wbase < N_NODES);  // N_NODES % 16 == 0 -> whole wave valid

  f32x4 acc[8];
  if (active) {
    bf16x8 afrag[8];
    int row = wbase + (lane & 15);
    int koff = (lane >> 4) * 8;
    const unsigned short* ap = aggB + (size_t)row * EMB + koff;
    const unsigned short* xp = xB + (size_t)row * EMB + koff;
#pragma unroll
    for (int kb = 0; kb < 4; kb++) afrag[kb] = *reinterpret_cast<const bf16x8*>(ap + kb * 32);
#pragma unroll
    for (int kb = 0; kb < 4; kb++) afrag[4 + kb] = *reinterpret_cast<const bf16x8*>(xp + kb * 32);
#pragma unroll
    for (int cb = 0; cb < 8; cb++) {
      f32x4 a = {0.0f, 0.0f, 0.0f, 0.0f};
#pragma unroll
      for (int kb = 0; kb < 8; kb++) {
        bf16x8 b = *reinterpret_cast<const bf16x8*>(pack + ((size_t)(cb * 8 + kb) * 64 + lane) * 8);
        a = __builtin_amdgcn_mfma_f32_16x16x32_bf16(afrag[kb], b, a, 0, 0, 0);
      }
      acc[cb] = a;
    }
  }

  if constexpr (!POOL) {
    if (active) {
#pragma unroll
      for (int cb = 0; cb < 8; cb++) {
        int col = cb * 16 + (lane & 15);
        float bias = bl[col];
#pragma unroll
        for (int r = 0; r < 4; r++) {
          float v = acc[cb][r] + bias;
          if (RELU) v = fmaxf(v, 0.0f);
          int rowl = (lane >> 4) * 4 + r;  // C/D: col=lane&15, row=(lane>>4)*4+r
          hout[(size_t)(wbase + rowl) * EMB + col] = f2bf(v);
        }
      }
    }
  } else {
    __shared__ float sh[64][130];
    __shared__ int sBatch[64];
    if (threadIdx.x < 64) {
      int node = blockIdx.x * 64 + threadIdx.x;
      sBatch[threadIdx.x] = batch[node < N_NODES ? node : (N_NODES - 1)];
    }
    if (active) {
#pragma unroll
      for (int cb = 0; cb < 8; cb++) {
        int col = cb * 16 + (lane & 15);
        float bias = bl[col];
#pragma unroll
        for (int r = 0; r < 4; r++) {
          float v = acc[cb][r] + bias;
          if (RELU) v = fmaxf(v, 0.0f);
          sh[w * 16 + (lane >> 4) * 4 + r][col] = v;
        }
      }
    }
    __syncthreads();
    // Segment reduction: thread t owns column (t&127), rows half*32..+31.
    int col = threadIdx.x & 127;
    int half = threadIdx.x >> 7;
    int nbase = blockIdx.x * 64 + half * 32;
    float rs = 0.0f, rm = -INFINITY;
    int cur = -1;
    for (int r = 0; r < 32; r++) {
      if (nbase + r >= N_NODES) break;
      int b = sBatch[half * 32 + r];
      float v = sh[half * 32 + r][col];
      if (b != cur) {
        if (cur >= 0) {
          atomicAdd(&gsum[cur * EMB + col], rs);
          atomicMax(&gmax[cur * EMB + col], fkey(rm));
        }
        cur = b; rs = 0.0f; rm = -INFINITY;
      }
      rs += v;
      rm = fmaxf(rm, v);
    }
    if (cur >= 0) {
      atomicAdd(&gsum[cur * EMB + col], rs);
      atomicMax(&gmax[cur * EMB + col], fkey(rm));
    }
  }
}

// batch_idx is SORTED -> per-graph counts via binary search, no atomics.
// One block, 128 threads; thread g finds lower_bound(batch, g).
__global__ __launch_bounds__(128) void gcnt_kernel(const int* __restrict__ batch,
                                                   float* __restrict__ gcnt) {
  __shared__ int lb[129];
  int g = threadIdx.x;
  int lo = 0, hi = N_NODES;
  while (lo < hi) {
    int mid = (lo + hi) >> 1;
    if (batch[mid] < g) lo = mid + 1; else hi = mid;
  }
  lb[g] = lo;
  if (g == 0) lb[128] = N_NODES;
  __syncthreads();
  gcnt[g] = (float)(lb[g + 1] - lb[g]);
}

// One block per graph, 128 threads = one per embedding dim.
__global__ __launch_bounds__(128) void readout_kernel(
    const float* __restrict__ gsum, const unsigned* __restrict__ gmax,
    const float* __restrict__ gcnt, const float* __restrict__ gfeat,
    const float* __restrict__ Wg, const float* __restrict__ bg,
    const float* __restrict__ Wo, const float* __restrict__ bo,
    float* __restrict__ out) {
  int g = blockIdx.x, d = threadIdx.x;
  float mean = gsum[g * EMB + d] / fmaxf(gcnt[g], 1.0f);
  float mx = fkey_inv(gmax[g * EMB + d]);
  float gfe = bg[d];
#pragma unroll
  for (int k = 0; k < G_FEAT; k++) gfe += gfeat[g * G_FEAT + k] * Wg[k * EMB + d];
  float l0 = mean * Wo[d * 2 + 0] + mx * Wo[(EMB + d) * 2 + 0] +
             gfe * Wo[(2 * EMB + d) * 2 + 0];
  float l1 = mean * Wo[d * 2 + 1] + mx * Wo[(EMB + d) * 2 + 1] +
             gfe * Wo[(2 * EMB + d) * 2 + 1];
  __shared__ float s0[128], s1[128];
  s0[d] = l0; s1[d] = l1;
  __syncthreads();
  for (int off = 64; off > 0; off >>= 1) {
    if (d < off) { s0[d] += s0[d + off]; s1[d] += s1[d + off]; }
    __syncthreads();
  }
  if (d == 0) {
    float a = s0[0] + bo[0];
    float b = s1[0] + bo[1];
    float m = fmaxf(a, b);
    float lse = m + logf(expf(a - m) + expf(b - m));
    out[g * 2 + 0] = a - lse;
    out[g * 2 + 1] = b - lse;
  }
}

extern "C" void kernel_launch(void* const* d_in, const int* in_sizes, int n_in,
                              void* d_out, int out_size, void* d_ws,
                              size_t ws_size, hipStream_t stream) {
  const float* x     = (const float*)d_in[0];
  const int*   edges = (const int*)d_in[1];
  const int*   batch = (const int*)d_in[2];
  const float* gfeat = (const float*)d_in[3];
  const float* W_l0  = (const float*)d_in[4];
  const float* b_l0  = (const float*)d_in[5];
  const float* W_r0  = (const float*)d_in[6];
  const float* W_l1  = (const float*)d_in[7];
  const float* b_l1  = (const float*)d_in[8];
  const float* W_r1  = (const float*)d_in[9];
  const float* W_g   = (const float*)d_in[10];
  const float* b_g   = (const float*)d_in[11];
  const float* W_o   = (const float*)d_in[12];
  const float* b_o   = (const float*)d_in[13];
  const int* srci = edges;
  const int* tgti = edges + N_EDGESC;

  // Workspace layout. Zeroed region first: [deg | cursor | gsum | gmax | gcnt]
  char* ws = (char*)d_ws;
  int*      deg      = (int*)ws;                            // N
  int*      cursor   = deg + N_NODES;                       // N
  float*    gsum     = (float*)(cursor + N_NODES);          // 128*128
  unsigned* gmax     = (unsigned*)(gsum + N_GRAPHS * EMB);  // 128*128
  float*    gcnt     = (float*)(gmax + N_GRAPHS * EMB);     // 128
  unsigned short* xB   = (unsigned short*)(gcnt + N_GRAPHS);      // N*128 bf16
  unsigned short* aggB = xB + (size_t)N_NODES * EMB;              // N*128 bf16
  unsigned short* hB   = aggB + (size_t)N_NODES * EMB;            // N*128 bf16
  unsigned short* pack0 = hB + (size_t)N_NODES * EMB;             // 32768 bf16
  unsigned short* pack1 = pack0 + 8 * 8 * 64 * 8;                 // 32768 bf16
  int*      ebuf     = (int*)(pack1 + 8 * 8 * 64 * 8);      // E
  int*      rowstart = ebuf + N_EDGESC;                     // N+1
  int*      partial  = rowstart + N_NODES + 1;              // N
  int*      blocksum = partial + N_NODES;                   // pad 128

  size_t zbytes = (size_t)((char*)xB - ws);
  hipMemsetAsync(d_ws, 0, zbytes, stream);

  dim3 b256(256);
  int egrid = (N_EDGESC + 255) / 256;

  // Conversions / packing (small)
  f2bf_kernel<<<(N_NODES * EMB / 4 + 255) / 256, b256, 0, stream>>>(x, xB,
                                                                    N_NODES * EMB / 4);
  pack_kernel<<<16, b256, 0, stream>>>(W_l0, W_r0, pack0);
  pack_kernel<<<16, b256, 0, stream>>>(W_l1, W_r1, pack1);

  // CSR build (shared by both layers)
  hist_kernel<<<egrid, b256, 0, stream>>>(tgti, deg);
  scan1_kernel<<<SCAN_NBLK, b256, 0, stream>>>(deg, partial, blocksum);
  scan2_kernel<<<1, 128, 0, stream>>>(blocksum);
  scan3_kernel<<<(N_NODES + 255) / 256, b256, 0, stream>>>(partial, blocksum,
                                                           rowstart);
  fill_kernel<<<egrid, b256, 0, stream>>>(srci, tgti, rowstart, cursor, ebuf);
  gcnt_kernel<<<1, 128, 0, stream>>>(batch, gcnt);

  int ngrid = (N_NODES + 63) / 64;   // 1563
  int agrid = (N_NODES + 7) / 8;     // 12500 (2 nodes/wave, 4 waves/block)

  // Layer 0
  aggb_kernel<<<agrid, b256, 0, stream>>>(xB, ebuf, rowstart, aggB);
  nodeMM_kernel<true, false><<<ngrid, b256, 0, stream>>>(
      aggB, xB, pack0, b_l0, nullptr, hB, nullptr, nullptr);

  // Layer 1
  aggb_kernel<<<agrid, b256, 0, stream>>>(hB, ebuf, rowstart, aggB);
  nodeMM_kernel<false, true><<<ngrid, b256, 0, stream>>>(
      aggB, hB, pack1, b_l1, batch, nullptr, gsum, gmax);

  // Readout
  readout_kernel<<<N_GRAPHS, 128, 0, stream>>>(gsum, gmax, gcnt, gfeat, W_g,
                                               b_g, W_o, b_o, (float*)d_out);
}

// Round 10
// 432.712 us; speedup vs baseline: 15.4078x; 1.0537x over previous
//
#include <hip/hip_runtime.h>

// Problem constants (match reference file)
#define N_NODES  100000
#define N_EDGESC 1600000
#define EMB      128
#define N_GRAPHS 128
#define G_FEAT   32

// Bucketed CSR build parameters
#define BUKSH    9                      // bucket = tgt >> 9 (512 nodes/bucket)
#define NBUK     196                    // ceil(100000 / 512)
#define CHUNK_E  2048
#define NBLK_E   ((N_EDGESC + CHUNK_E - 1) / CHUNK_E)  // 782

typedef __attribute__((ext_vector_type(8))) short bf16x8;
typedef __attribute__((ext_vector_type(4))) float f32x4;

// Order-preserving float -> uint key for atomicMax-based float max.
__device__ __forceinline__ unsigned fkey(float f) {
  unsigned u = __float_as_uint(f);
  return (u & 0x80000000u) ? ~u : (u | 0x80000000u);
}
__device__ __forceinline__ float fkey_inv(unsigned k) {
  return (k & 0x80000000u) ? __uint_as_float(k & 0x7FFFFFFFu)
                           : __uint_as_float(~k);
}
__device__ __forceinline__ float bf2f(unsigned short u) {
  return __uint_as_float(((unsigned)u) << 16);
}
__device__ __forceinline__ unsigned short f2bf(float f) {  // RNE
  unsigned u = __float_as_uint(f);
  u += 0x7fffu + ((u >> 16) & 1u);
  return (unsigned short)(u >> 16);
}

// ---------------- dtype conversion / weight packing ----------------

__global__ __launch_bounds__(256) void f2bf_kernel(const float* __restrict__ in,
                                                   unsigned short* __restrict__ out,
                                                   int n4) {
  int i = blockIdx.x * blockDim.x + threadIdx.x;
  if (i >= n4) return;
  float4 v = reinterpret_cast<const float4*>(in)[i];
  uint2 o;
  o.x = (unsigned)f2bf(v.x) | ((unsigned)f2bf(v.y) << 16);
  o.y = (unsigned)f2bf(v.z) | ((unsigned)f2bf(v.w) << 16);
  reinterpret_cast<uint2*>(out)[i] = o;
}

// Pack stacked weights [Wl(128x128); Wr(128x128)] -> MFMA B-fragment order:
// pack[((cb*8+kb)*64+lane)*8 + j] = W[k = kb*32+(lane>>4)*8+j][col = cb*16+(lane&15)]
__global__ __launch_bounds__(256) void pack_kernel(const float* __restrict__ Wl,
                                                   const float* __restrict__ Wr,
                                                   unsigned short* __restrict__ pack) {
  int id = blockIdx.x * blockDim.x + threadIdx.x;
  if (id >= 4096) return;
  int lane = id & 63;
  int kb = (id >> 6) & 7;
  int cb = id >> 9;
  int col = cb * 16 + (lane & 15);
  int k0 = kb * 32 + (lane >> 4) * 8;
  unsigned short v[8];
#pragma unroll
  for (int j = 0; j < 8; j++) {
    int k = k0 + j;
    float w = (k < 128) ? Wl[k * 128 + col] : Wr[(k - 128) * 128 + col];
    v[j] = f2bf(w);
  }
  uint4 o;
  o.x = (unsigned)v[0] | ((unsigned)v[1] << 16);
  o.y = (unsigned)v[2] | ((unsigned)v[3] << 16);
  o.z = (unsigned)v[4] | ((unsigned)v[5] << 16);
  o.w = (unsigned)v[6] | ((unsigned)v[7] << 16);
  *reinterpret_cast<uint4*>(pack + (size_t)id * 8) = o;
}

// ---------------- bucketed CSR build (write-locality-ordered) ----------------

// A: per-chunk LDS histogram over 196 coarse buckets.
__global__ __launch_bounds__(256) void bhistA_kernel(const int* __restrict__ tgti,
                                                     int* __restrict__ counts) {
  __shared__ int h[NBUK];
  for (int i = threadIdx.x; i < NBUK; i += 256) h[i] = 0;
  __syncthreads();
  int base = blockIdx.x * CHUNK_E;
  for (int i = threadIdx.x; i < CHUNK_E; i += 256) {
    int e = base + i;
    if (e < N_EDGESC) atomicAdd(&h[tgti[e] >> BUKSH], 1);
  }
  __syncthreads();
  for (int i = threadIdx.x; i < NBUK; i += 256)
    counts[blockIdx.x * NBUK + i] = h[i];
}

// B: bucket bases + stable per-(chunk,bucket) offsets. One block.
__global__ __launch_bounds__(256) void bscanB_kernel(const int* __restrict__ counts,
                                                     int* __restrict__ offsets,
                                                     int* __restrict__ bucketBase) {
  __shared__ int tot[NBUK];
  __shared__ int pre[NBUK + 1];
  int b = threadIdx.x;
  if (b < NBUK) {
    int s = 0;
    for (int blk = 0; blk < NBLK_E; blk++) s += counts[blk * NBUK + b];
    tot[b] = s;
  }
  __syncthreads();
  if (threadIdx.x == 0) {
    int run = 0;
    for (int i = 0; i < NBUK; i++) { pre[i] = run; run += tot[i]; }
    pre[NBUK] = run;  // == N_EDGESC
  }
  __syncthreads();
  if (b < NBUK) {
    bucketBase[b] = pre[b];
    if (b == 0) bucketBase[NBUK] = pre[NBUK];
    int run = pre[b];
    for (int blk = 0; blk < NBLK_E; blk++) {
      offsets[blk * NBUK + b] = run;
      run += counts[blk * NBUK + b];
    }
  }
}

// C: scatter packed (src | local_tgt<<17) into bucket-contiguous regions.
__global__ __launch_bounds__(256) void bscatC_kernel(const int* __restrict__ srci,
                                                     const int* __restrict__ tgti,
                                                     const int* __restrict__ offsets,
                                                     unsigned* __restrict__ bucketed) {
  __shared__ int cur[NBUK];
  for (int i = threadIdx.x; i < NBUK; i += 256)
    cur[i] = offsets[blockIdx.x * NBUK + i];
  __syncthreads();
  int base = blockIdx.x * CHUNK_E;
  for (int i = threadIdx.x; i < CHUNK_E; i += 256) {
    int e = base + i;
    if (e < N_EDGESC) {
      int t = tgti[e];
      int bk = t >> BUKSH;
      int pos = atomicAdd(&cur[bk], 1);
      bucketed[pos] = (unsigned)srci[e] |
                      ((unsigned)(t & ((1 << BUKSH) - 1)) << 17);
    }
  }
}

// D: one block per bucket -> per-node degree, rowstart, and ebuf fill
// (all writes land in this block's own 32 KB region: single-CU locality).
__global__ __launch_bounds__(256) void bcsrD_kernel(const unsigned* __restrict__ bucketed,
                                                    const int* __restrict__ bucketBase,
                                                    int* __restrict__ rowstart,
                                                    int* __restrict__ ebuf) {
  __shared__ int deg[512];
  __shared__ int pre[512];
  __shared__ int sh2[256];
  int bk = blockIdx.x;
  int node0 = bk << BUKSH;
  int nn = min(512, N_NODES - node0);
  int beg = bucketBase[bk], end = bucketBase[bk + 1];
  for (int i = threadIdx.x; i < 512; i += 256) deg[i] = 0;
  __syncthreads();
  for (int j = beg + threadIdx.x; j < end; j += 256)
    atomicAdd(&deg[bucketed[j] >> 17], 1);
  __syncthreads();
  // block exclusive scan over 512 (2 per thread)
  int t = threadIdx.x;
  int v0 = deg[2 * t], v1 = deg[2 * t + 1];
  sh2[t] = v0 + v1;
  __syncthreads();
  for (int off = 1; off < 256; off <<= 1) {
    int val = (t >= off) ? sh2[t - off] : 0;
    __syncthreads();
    if (t >= off) sh2[t] += val;
    __syncthreads();
  }
  int ex = sh2[t] - v0 - v1;
  pre[2 * t] = ex;
  pre[2 * t + 1] = ex + v0;
  __syncthreads();
  for (int i = threadIdx.x; i < nn; i += 256) rowstart[node0 + i] = beg + pre[i];
  if (bk == 0 && threadIdx.x == 0) rowstart[N_NODES] = N_EDGESC;
  // reuse deg[] as local cursor = pre[]
  for (int i = threadIdx.x; i < 512; i += 256) deg[i] = pre[i];
  __syncthreads();
  for (int j = beg + threadIdx.x; j < end; j += 256) {
    unsigned p = bucketed[j];
    int ln = p >> 17;
    int pos = atomicAdd(&deg[ln], 1);
    ebuf[beg + pos] = (int)(p & 0x1FFFFu);
  }
}

// ---------------- mean aggregation (bf16 gather, no atomics) ----------------
// 2 nodes per wave: half-wave of 32 lanes per node, lane owns 4 dims (8 B).
// Edge loop unrolled x4 -> 4 independent row gathers in flight (ILP).
__global__ __launch_bounds__(256) void aggb_kernel(const unsigned short* __restrict__ featB,
                                                   const int* __restrict__ ebuf,
                                                   const int* __restrict__ rowstart,
                                                   unsigned short* __restrict__ aggB) {
  int wid = (blockIdx.x * 256 + threadIdx.x) >> 6;  // global wave id
  int lane = threadIdx.x & 63;
  int node = wid * 2 + (lane >> 5);
  if (node >= N_NODES) return;
  int l = lane & 31;
  int beg = rowstart[node], end = rowstart[node + 1];
  int off = l * 4;  // 4 bf16 = 8 B per lane
  float a0 = 0.0f, a1 = 0.0f, a2 = 0.0f, a3 = 0.0f;
  int j = beg;
  for (; j + 4 <= end; j += 4) {
    int s0 = ebuf[j], s1 = ebuf[j + 1], s2 = ebuf[j + 2], s3 = ebuf[j + 3];
    uint2 u0 = *reinterpret_cast<const uint2*>(featB + (size_t)s0 * EMB + off);
    uint2 u1 = *reinterpret_cast<const uint2*>(featB + (size_t)s1 * EMB + off);
    uint2 u2 = *reinterpret_cast<const uint2*>(featB + (size_t)s2 * EMB + off);
    uint2 u3 = *reinterpret_cast<const uint2*>(featB + (size_t)s3 * EMB + off);
    a0 += bf2f((unsigned short)(u0.x & 0xffffu)) + bf2f((unsigned short)(u1.x & 0xffffu)) +
          bf2f((unsigned short)(u2.x & 0xffffu)) + bf2f((unsigned short)(u3.x & 0xffffu));
    a1 += bf2f((unsigned short)(u0.x >> 16)) + bf2f((unsigned short)(u1.x >> 16)) +
          bf2f((unsigned short)(u2.x >> 16)) + bf2f((unsigned short)(u3.x >> 16));
    a2 += bf2f((unsigned short)(u0.y & 0xffffu)) + bf2f((unsigned short)(u1.y & 0xffffu)) +
          bf2f((unsigned short)(u2.y & 0xffffu)) + bf2f((unsigned short)(u3.y & 0xffffu));
    a3 += bf2f((unsigned short)(u0.y >> 16)) + bf2f((unsigned short)(u1.y >> 16)) +
          bf2f((unsigned short)(u2.y >> 16)) + bf2f((unsigned short)(u3.y >> 16));
  }
  for (; j < end; j++) {
    int s = ebuf[j];
    uint2 u = *reinterpret_cast<const uint2*>(featB + (size_t)s * EMB + off);
    a0 += bf2f((unsigned short)(u.x & 0xffffu));
    a1 += bf2f((unsigned short)(u.x >> 16));
    a2 += bf2f((unsigned short)(u.y & 0xffffu));
    a3 += bf2f((unsigned short)(u.y >> 16));
  }
  float inv = 1.0f / fmaxf((float)(end - beg), 1.0f);
  uint2 o;
  o.x = (unsigned)f2bf(a0 * inv) | ((unsigned)f2bf(a1 * inv) << 16);
  o.y = (unsigned)f2bf(a2 * inv) | ((unsigned)f2bf(a3 * inv) << 16);
  *reinterpret_cast<uint2*>(aggB + (size_t)node * EMB + off) = o;
}

// ---------------- node GEMM via MFMA: out = [relu]([agg|x] @ [Wl;Wr] + bl) ----
// 64 nodes/block, 4 waves x 16 rows. A-frags direct from global; B from pack.
// POOL: stage to LDS, segment-reduce per column (batch_idx sorted), few atomics.
template <bool RELU, bool POOL>
__global__ __launch_bounds__(256) void nodeMM_kernel(
    const unsigned short* __restrict__ aggB, const unsigned short* __restrict__ xB,
    const unsigned short* __restrict__ pack, const float* __restrict__ bl,
    const int* __restrict__ batch, unsigned short* __restrict__ hout,
    float* __restrict__ gsum, unsigned* __restrict__ gmax) {
  int w = threadIdx.x >> 6;
  int lane = threadIdx.x & 63;
  int wbase = blockIdx.x * 64 + w * 16;
  bool active = (wbase < N_NODES);  // N_NODES % 16 == 0 -> whole wave valid

  f32x4 acc[8];
  if (active) {
    bf16x8 afrag[8];
    int row = wbase + (lane & 15);
    int koff = (lane >> 4) * 8;
    const unsigned short* ap = aggB + (size_t)row * EMB + koff;
    const unsigned short* xp = xB + (size_t)row * EMB + koff;
#pragma unroll
    for (int kb = 0; kb < 4; kb++) afrag[kb] = *reinterpret_cast<const bf16x8*>(ap + kb * 32);
#pragma unroll
    for (int kb = 0; kb < 4; kb++) afrag[4 + kb] = *reinterpret_cast<const bf16x8*>(xp + kb * 32);
#pragma unroll
    for (int cb = 0; cb < 8; cb++) {
      f32x4 a = {0.0f, 0.0f, 0.0f, 0.0f};
#pragma unroll
      for (int kb = 0; kb < 8; kb++) {
        bf16x8 b = *reinterpret_cast<const bf16x8*>(pack + ((size_t)(cb * 8 + kb) * 64 + lane) * 8);
        a = __builtin_amdgcn_mfma_f32_16x16x32_bf16(afrag[kb], b, a, 0, 0, 0);
      }
      acc[cb] = a;
    }
  }

  if constexpr (!POOL) {
    if (active) {
#pragma unroll
      for (int cb = 0; cb < 8; cb++) {
        int col = cb * 16 + (lane & 15);
        float bias = bl[col];
#pragma unroll
        for (int r = 0; r < 4; r++) {
          float v = acc[cb][r] + bias;
          if (RELU) v = fmaxf(v, 0.0f);
          int rowl = (lane >> 4) * 4 + r;  // C/D: col=lane&15, row=(lane>>4)*4+r
          hout[(size_t)(wbase + rowl) * EMB + col] = f2bf(v);
        }
      }
    }
  } else {
    __shared__ float sh[64][130];
    __shared__ int sBatch[64];
    if (threadIdx.x < 64) {
      int node = blockIdx.x * 64 + threadIdx.x;
      sBatch[threadIdx.x] = batch[node < N_NODES ? node : (N_NODES - 1)];
    }
    if (active) {
#pragma unroll
      for (int cb = 0; cb < 8; cb++) {
        int col = cb * 16 + (lane & 15);
        float bias = bl[col];
#pragma unroll
        for (int r = 0; r < 4; r++) {
          float v = acc[cb][r] + bias;
          if (RELU) v = fmaxf(v, 0.0f);
          sh[w * 16 + (lane >> 4) * 4 + r][col] = v;
        }
      }
    }
    __syncthreads();
    // Segment reduction: thread t owns column (t&127), rows half*32..+31.
    int col = threadIdx.x & 127;
    int half = threadIdx.x >> 7;
    int nbase = blockIdx.x * 64 + half * 32;
    float rs = 0.0f, rm = -INFINITY;
    int cur = -1;
    for (int r = 0; r < 32; r++) {
      if (nbase + r >= N_NODES) break;
      int b = sBatch[half * 32 + r];
      float v = sh[half * 32 + r][col];
      if (b != cur) {
        if (cur >= 0) {
          atomicAdd(&gsum[cur * EMB + col], rs);
          atomicMax(&gmax[cur * EMB + col], fkey(rm));
        }
        cur = b; rs = 0.0f; rm = -INFINITY;
      }
      rs += v;
      rm = fmaxf(rm, v);
    }
    if (cur >= 0) {
      atomicAdd(&gsum[cur * EMB + col], rs);
      atomicMax(&gmax[cur * EMB + col], fkey(rm));
    }
  }
}

// batch_idx is SORTED -> per-graph counts via binary search, no atomics.
__global__ __launch_bounds__(128) void gcnt_kernel(const int* __restrict__ batch,
                                                   float* __restrict__ gcnt) {
  __shared__ int lb[129];
  int g = threadIdx.x;
  int lo = 0, hi = N_NODES;
  while (lo < hi) {
    int mid = (lo + hi) >> 1;
    if (batch[mid] < g) lo = mid + 1; else hi = mid;
  }
  lb[g] = lo;
  if (g == 0) lb[128] = N_NODES;
  __syncthreads();
  gcnt[g] = (float)(lb[g + 1] - lb[g]);
}

// One block per graph, 128 threads = one per embedding dim.
__global__ __launch_bounds__(128) void readout_kernel(
    const float* __restrict__ gsum, const unsigned* __restrict__ gmax,
    const float* __restrict__ gcnt, const float* __restrict__ gfeat,
    const float* __restrict__ Wg, const float* __restrict__ bg,
    const float* __restrict__ Wo, const float* __restrict__ bo,
    float* __restrict__ out) {
  int g = blockIdx.x, d = threadIdx.x;
  float mean = gsum[g * EMB + d] / fmaxf(gcnt[g], 1.0f);
  float mx = fkey_inv(gmax[g * EMB + d]);
  float gfe = bg[d];
#pragma unroll
  for (int k = 0; k < G_FEAT; k++) gfe += gfeat[g * G_FEAT + k] * Wg[k * EMB + d];
  float l0 = mean * Wo[d * 2 + 0] + mx * Wo[(EMB + d) * 2 + 0] +
             gfe * Wo[(2 * EMB + d) * 2 + 0];
  float l1 = mean * Wo[d * 2 + 1] + mx * Wo[(EMB + d) * 2 + 1] +
             gfe * Wo[(2 * EMB + d) * 2 + 1];
  __shared__ float s0[128], s1[128];
  s0[d] = l0; s1[d] = l1;
  __syncthreads();
  for (int off = 64; off > 0; off >>= 1) {
    if (d < off) { s0[d] += s0[d + off]; s1[d] += s1[d + off]; }
    __syncthreads();
  }
  if (d == 0) {
    float a = s0[0] + bo[0];
    float b = s1[0] + bo[1];
    float m = fmaxf(a, b);
    float lse = m + logf(expf(a - m) + expf(b - m));
    out[g * 2 + 0] = a - lse;
    out[g * 2 + 1] = b - lse;
  }
}

extern "C" void kernel_launch(void* const* d_in, const int* in_sizes, int n_in,
                              void* d_out, int out_size, void* d_ws,
                              size_t ws_size, hipStream_t stream) {
  const float* x     = (const float*)d_in[0];
  const int*   edges = (const int*)d_in[1];
  const int*   batch = (const int*)d_in[2];
  const float* gfeat = (const float*)d_in[3];
  const float* W_l0  = (const float*)d_in[4];
  const float* b_l0  = (const float*)d_in[5];
  const float* W_r0  = (const float*)d_in[6];
  const float* W_l1  = (const float*)d_in[7];
  const float* b_l1  = (const float*)d_in[8];
  const float* W_r1  = (const float*)d_in[9];
  const float* W_g   = (const float*)d_in[10];
  const float* b_g   = (const float*)d_in[11];
  const float* W_o   = (const float*)d_in[12];
  const float* b_o   = (const float*)d_in[13];
  const int* srci = edges;
  const int* tgti = edges + N_EDGESC;

  // Workspace layout. Zeroed region first: [gsum | gmax | gcnt]
  char* ws = (char*)d_ws;
  float*    gsum     = (float*)ws;                          // 128*128
  unsigned* gmax     = (unsigned*)(gsum + N_GRAPHS * EMB);  // 128*128
  float*    gcnt     = (float*)(gmax + N_GRAPHS * EMB);     // 128
  unsigned short* xB   = (unsigned short*)(gcnt + N_GRAPHS);      // N*128 bf16
  unsigned short* aggB = xB + (size_t)N_NODES * EMB;              // N*128 bf16
  unsigned short* hB   = aggB + (size_t)N_NODES * EMB;            // N*128 bf16
  unsigned short* pack0 = hB + (size_t)N_NODES * EMB;             // 32768 bf16
  unsigned short* pack1 = pack0 + 8 * 8 * 64 * 8;                 // 32768 bf16
  int*      ebuf     = (int*)(pack1 + 8 * 8 * 64 * 8);      // E
  int*      rowstart = ebuf + N_EDGESC;                     // N+1
  int*      bucketBase = rowstart + N_NODES + 1;            // NBUK+1
  // CSR-build scratch aliased into regions written only AFTER the build:
  int*      counts   = (int*)aggB;                          // NBLK_E*NBUK ints (<1.3MB)
  int*      offsets  = counts + NBLK_E * NBUK;              // NBLK_E*NBUK ints
  unsigned* bucketed = (unsigned*)hB;                       // E uints (6.4MB)

  // Zero gsum/gmax/gcnt only (131.5 KB).
  size_t zbytes = (size_t)((char*)xB - ws);
  hipMemsetAsync(d_ws, 0, zbytes, stream);

  dim3 b256(256);

  // Conversions / packing (small)
  f2bf_kernel<<<(N_NODES * EMB / 4 + 255) / 256, b256, 0, stream>>>(x, xB,
                                                                    N_NODES * EMB / 4);
  pack_kernel<<<16, b256, 0, stream>>>(W_l0, W_r0, pack0);
  pack_kernel<<<16, b256, 0, stream>>>(W_l1, W_r1, pack1);

  // Bucketed CSR build (shared by both layers)
  bhistA_kernel<<<NBLK_E, b256, 0, stream>>>(tgti, counts);
  bscanB_kernel<<<1, b256, 0, stream>>>(counts, offsets, bucketBase);
  bscatC_kernel<<<NBLK_E, b256, 0, stream>>>(srci, tgti, offsets, bucketed);
  bcsrD_kernel<<<NBUK, b256, 0, stream>>>(bucketed, bucketBase, rowstart, ebuf);
  gcnt_kernel<<<1, 128, 0, stream>>>(batch, gcnt);

  int ngrid = (N_NODES + 63) / 64;   // 1563
  int agrid = (N_NODES + 7) / 8;     // 12500 (2 nodes/wave, 4 waves/block)

  // Layer 0
  aggb_kernel<<<agrid, b256, 0, stream>>>(xB, ebuf, rowstart, aggB);
  nodeMM_kernel<true, false><<<ngrid, b256, 0, stream>>>(
      aggB, xB, pack0, b_l0, nullptr, hB, nullptr, nullptr);

  // Layer 1
  aggb_kernel<<<agrid, b256, 0, stream>>>(hB, ebuf, rowstart, aggB);
  nodeMM_kernel<false, true><<<ngrid, b256, 0, stream>>>(
      aggB, hB, pack1, b_l1, batch, nullptr, gsum, gmax);

  // Readout
  readout_kernel<<<N_GRAPHS, 128, 0, stream>>>(gsum, gmax, gcnt, gfeat, W_g,
                                               b_g, W_o, b_o, (float*)d_out);
}

// Round 11
// 359.178 us; speedup vs baseline: 18.5622x; 1.2047x over previous
//
#include <hip/hip_runtime.h>

// Problem constants (match reference file)
#define N_NODES  100000
#define N_EDGESC 1600000
#define EMB      128
#define N_GRAPHS 128
#define G_FEAT   32

// Bucketed CSR build parameters
#define BUKSH    9                      // bucket = tgt >> 9 (512 nodes/bucket)
#define NBUK     196                    // ceil(100000 / 512)
#define CHUNK_E  2048
#define NBLK_E   ((N_EDGESC + CHUNK_E - 1) / CHUNK_E)  // 782

typedef __attribute__((ext_vector_type(8))) short bf16x8;
typedef __attribute__((ext_vector_type(4))) float f32x4;

// Order-preserving float -> uint key for atomicMax-based float max.
__device__ __forceinline__ unsigned fkey(float f) {
  unsigned u = __float_as_uint(f);
  return (u & 0x80000000u) ? ~u : (u | 0x80000000u);
}
__device__ __forceinline__ float fkey_inv(unsigned k) {
  return (k & 0x80000000u) ? __uint_as_float(k & 0x7FFFFFFFu)
                           : __uint_as_float(~k);
}
__device__ __forceinline__ float bf2f(unsigned short u) {
  return __uint_as_float(((unsigned)u) << 16);
}
__device__ __forceinline__ unsigned short f2bf(float f) {  // RNE
  unsigned u = __float_as_uint(f);
  u += 0x7fffu + ((u >> 16) & 1u);
  return (unsigned short)(u >> 16);
}

// ---------------- dtype conversion / weight packing ----------------

__global__ __launch_bounds__(256) void f2bf_kernel(const float* __restrict__ in,
                                                   unsigned short* __restrict__ out,
                                                   int n4) {
  int i = blockIdx.x * blockDim.x + threadIdx.x;
  if (i >= n4) return;
  float4 v = reinterpret_cast<const float4*>(in)[i];
  uint2 o;
  o.x = (unsigned)f2bf(v.x) | ((unsigned)f2bf(v.y) << 16);
  o.y = (unsigned)f2bf(v.z) | ((unsigned)f2bf(v.w) << 16);
  reinterpret_cast<uint2*>(out)[i] = o;
}

// Pack stacked weights [Wl(128x128); Wr(128x128)] -> MFMA B-fragment order:
// pack[((cb*8+kb)*64+lane)*8 + j] = W[k = kb*32+(lane>>4)*8+j][col = cb*16+(lane&15)]
__global__ __launch_bounds__(256) void pack_kernel(const float* __restrict__ Wl,
                                                   const float* __restrict__ Wr,
                                                   unsigned short* __restrict__ pack) {
  int id = blockIdx.x * blockDim.x + threadIdx.x;
  if (id >= 4096) return;
  int lane = id & 63;
  int kb = (id >> 6) & 7;
  int cb = id >> 9;
  int col = cb * 16 + (lane & 15);
  int k0 = kb * 32 + (lane >> 4) * 8;
  unsigned short v[8];
#pragma unroll
  for (int j = 0; j < 8; j++) {
    int k = k0 + j;
    float w = (k < 128) ? Wl[k * 128 + col] : Wr[(k - 128) * 128 + col];
    v[j] = f2bf(w);
  }
  uint4 o;
  o.x = (unsigned)v[0] | ((unsigned)v[1] << 16);
  o.y = (unsigned)v[2] | ((unsigned)v[3] << 16);
  o.z = (unsigned)v[4] | ((unsigned)v[5] << 16);
  o.w = (unsigned)v[6] | ((unsigned)v[7] << 16);
  *reinterpret_cast<uint4*>(pack + (size_t)id * 8) = o;
}

// ---------------- bucketed CSR build (write-locality-ordered) ----------------

// A: per-chunk LDS histogram over 196 coarse buckets.
__global__ __launch_bounds__(256) void bhistA_kernel(const int* __restrict__ tgti,
                                                     int* __restrict__ counts) {
  __shared__ int h[NBUK];
  for (int i = threadIdx.x; i < NBUK; i += 256) h[i] = 0;
  __syncthreads();
  int base = blockIdx.x * CHUNK_E;
  for (int i = threadIdx.x; i < CHUNK_E; i += 256) {
    int e = base + i;
    if (e < N_EDGESC) atomicAdd(&h[tgti[e] >> BUKSH], 1);
  }
  __syncthreads();
  for (int i = threadIdx.x; i < NBUK; i += 256)
    counts[blockIdx.x * NBUK + i] = h[i];
}

// B1: per-bucket totals. Block b tree-reduces its counts column.
__global__ __launch_bounds__(256) void bsumB1_kernel(const int* __restrict__ counts,
                                                     int* __restrict__ tot) {
  __shared__ int sh[256];
  int b = blockIdx.x;
  int t = threadIdx.x;
  int s = 0;
  for (int blk = t; blk < NBLK_E; blk += 256) s += counts[blk * NBUK + b];
  sh[t] = s;
  __syncthreads();
  for (int off = 128; off > 0; off >>= 1) {
    if (t < off) sh[t] += sh[t + off];
    __syncthreads();
  }
  if (t == 0) tot[b] = sh[0];
}

// B1b: exclusive scan of 196 totals -> bucketBase. One block (tiny).
__global__ __launch_bounds__(256) void bbaseB_kernel(const int* __restrict__ tot,
                                                     int* __restrict__ bucketBase) {
  __shared__ int sh[256];
  int t = threadIdx.x;
  int v = (t < NBUK) ? tot[t] : 0;
  sh[t] = v;
  __syncthreads();
  for (int off = 1; off < 256; off <<= 1) {
    int val = (t >= off) ? sh[t - off] : 0;
    __syncthreads();
    if (t >= off) sh[t] += val;
    __syncthreads();
  }
  if (t < NBUK) bucketBase[t] = sh[t] - v;
  if (t == 0) bucketBase[NBUK] = sh[NBUK - 1];  // == N_EDGESC
}

// B2: per-bucket exclusive scan over chunks -> stable offsets.
__global__ __launch_bounds__(256) void boffB2_kernel(const int* __restrict__ counts,
                                                     const int* __restrict__ bucketBase,
                                                     int* __restrict__ offsets) {
  __shared__ int sh[256];
  int b = blockIdx.x;
  int t = threadIdx.x;
  int v[4], s = 0;
#pragma unroll
  for (int i = 0; i < 4; i++) {
    int blk = t * 4 + i;
    v[i] = (blk < NBLK_E) ? counts[blk * NBUK + b] : 0;
    s += v[i];
  }
  sh[t] = s;
  __syncthreads();
  for (int off = 1; off < 256; off <<= 1) {
    int val = (t >= off) ? sh[t - off] : 0;
    __syncthreads();
    if (t >= off) sh[t] += val;
    __syncthreads();
  }
  int run = bucketBase[b] + sh[t] - s;
#pragma unroll
  for (int i = 0; i < 4; i++) {
    int blk = t * 4 + i;
    if (blk < NBLK_E) offsets[blk * NBUK + b] = run;
    run += v[i];
  }
}

// C: scatter packed (src | local_tgt<<17) into bucket-contiguous regions.
__global__ __launch_bounds__(256) void bscatC_kernel(const int* __restrict__ srci,
                                                     const int* __restrict__ tgti,
                                                     const int* __restrict__ offsets,
                                                     unsigned* __restrict__ bucketed) {
  __shared__ int cur[NBUK];
  for (int i = threadIdx.x; i < NBUK; i += 256)
    cur[i] = offsets[blockIdx.x * NBUK + i];
  __syncthreads();
  int base = blockIdx.x * CHUNK_E;
  for (int i = threadIdx.x; i < CHUNK_E; i += 256) {
    int e = base + i;
    if (e < N_EDGESC) {
      int t = tgti[e];
      int bk = t >> BUKSH;
      int pos = atomicAdd(&cur[bk], 1);
      bucketed[pos] = (unsigned)srci[e] |
                      ((unsigned)(t & ((1 << BUKSH) - 1)) << 17);
    }
  }
}

// D: one block per bucket -> per-node degree, rowstart, and ebuf fill
// (all writes land in this block's own 32 KB region: single-CU locality).
__global__ __launch_bounds__(256) void bcsrD_kernel(const unsigned* __restrict__ bucketed,
                                                    const int* __restrict__ bucketBase,
                                                    int* __restrict__ rowstart,
                                                    int* __restrict__ ebuf) {
  __shared__ int deg[512];
  __shared__ int pre[512];
  __shared__ int sh2[256];
  int bk = blockIdx.x;
  int node0 = bk << BUKSH;
  int nn = min(512, N_NODES - node0);
  int beg = bucketBase[bk], end = bucketBase[bk + 1];
  for (int i = threadIdx.x; i < 512; i += 256) deg[i] = 0;
  __syncthreads();
  for (int j = beg + threadIdx.x; j < end; j += 256)
    atomicAdd(&deg[bucketed[j] >> 17], 1);
  __syncthreads();
  // block exclusive scan over 512 (2 per thread)
  int t = threadIdx.x;
  int v0 = deg[2 * t], v1 = deg[2 * t + 1];
  sh2[t] = v0 + v1;
  __syncthreads();
  for (int off = 1; off < 256; off <<= 1) {
    int val = (t >= off) ? sh2[t - off] : 0;
    __syncthreads();
    if (t >= off) sh2[t] += val;
    __syncthreads();
  }
  int ex = sh2[t] - v0 - v1;
  pre[2 * t] = ex;
  pre[2 * t + 1] = ex + v0;
  __syncthreads();
  for (int i = threadIdx.x; i < nn; i += 256) rowstart[node0 + i] = beg + pre[i];
  if (bk == 0 && threadIdx.x == 0) rowstart[N_NODES] = N_EDGESC;
  // reuse deg[] as local cursor = pre[]
  for (int i = threadIdx.x; i < 512; i += 256) deg[i] = pre[i];
  __syncthreads();
  for (int j = beg + threadIdx.x; j < end; j += 256) {
    unsigned p = bucketed[j];
    int ln = p >> 17;
    int pos = atomicAdd(&deg[ln], 1);
    ebuf[beg + pos] = (int)(p & 0x1FFFFu);
  }
}

// ---------------- mean aggregation (bf16 gather, no atomics) ----------------
// 2 nodes per wave: half-wave of 32 lanes per node, lane owns 4 dims (8 B).
// Edge loop unrolled x4 -> 4 independent row gathers in flight (ILP).
__global__ __launch_bounds__(256) void aggb_kernel(const unsigned short* __restrict__ featB,
                                                   const int* __restrict__ ebuf,
                                                   const int* __restrict__ rowstart,
                                                   unsigned short* __restrict__ aggB) {
  int wid = (blockIdx.x * 256 + threadIdx.x) >> 6;  // global wave id
  int lane = threadIdx.x & 63;
  int node = wid * 2 + (lane >> 5);
  if (node >= N_NODES) return;
  int l = lane & 31;
  int beg = rowstart[node], end = rowstart[node + 1];
  int off = l * 4;  // 4 bf16 = 8 B per lane
  float a0 = 0.0f, a1 = 0.0f, a2 = 0.0f, a3 = 0.0f;
  int j = beg;
  for (; j + 4 <= end; j += 4) {
    int s0 = ebuf[j], s1 = ebuf[j + 1], s2 = ebuf[j + 2], s3 = ebuf[j + 3];
    uint2 u0 = *reinterpret_cast<const uint2*>(featB + (size_t)s0 * EMB + off);
    uint2 u1 = *reinterpret_cast<const uint2*>(featB + (size_t)s1 * EMB + off);
    uint2 u2 = *reinterpret_cast<const uint2*>(featB + (size_t)s2 * EMB + off);
    uint2 u3 = *reinterpret_cast<const uint2*>(featB + (size_t)s3 * EMB + off);
    a0 += bf2f((unsigned short)(u0.x & 0xffffu)) + bf2f((unsigned short)(u1.x & 0xffffu)) +
          bf2f((unsigned short)(u2.x & 0xffffu)) + bf2f((unsigned short)(u3.x & 0xffffu));
    a1 += bf2f((unsigned short)(u0.x >> 16)) + bf2f((unsigned short)(u1.x >> 16)) +
          bf2f((unsigned short)(u2.x >> 16)) + bf2f((unsigned short)(u3.x >> 16));
    a2 += bf2f((unsigned short)(u0.y & 0xffffu)) + bf2f((unsigned short)(u1.y & 0xffffu)) +
          bf2f((unsigned short)(u2.y & 0xffffu)) + bf2f((unsigned short)(u3.y & 0xffffu));
    a3 += bf2f((unsigned short)(u0.y >> 16)) + bf2f((unsigned short)(u1.y >> 16)) +
          bf2f((unsigned short)(u2.y >> 16)) + bf2f((unsigned short)(u3.y >> 16));
  }
  for (; j < end; j++) {
    int s = ebuf[j];
    uint2 u = *reinterpret_cast<const uint2*>(featB + (size_t)s * EMB + off);
    a0 += bf2f((unsigned short)(u.x & 0xffffu));
    a1 += bf2f((unsigned short)(u.x >> 16));
    a2 += bf2f((unsigned short)(u.y & 0xffffu));
    a3 += bf2f((unsigned short)(u.y >> 16));
  }
  float inv = 1.0f / fmaxf((float)(end - beg), 1.0f);
  uint2 o;
  o.x = (unsigned)f2bf(a0 * inv) | ((unsigned)f2bf(a1 * inv) << 16);
  o.y = (unsigned)f2bf(a2 * inv) | ((unsigned)f2bf(a3 * inv) << 16);
  *reinterpret_cast<uint2*>(aggB + (size_t)node * EMB + off) = o;
}

// ---------------- node GEMM via MFMA: out = [relu]([agg|x] @ [Wl;Wr] + bl) ----
// 64 nodes/block, 4 waves x 16 rows. A-frags direct from global; B from pack.
// POOL: stage to LDS, segment-reduce per column (batch_idx sorted), few atomics.
template <bool RELU, bool POOL>
__global__ __launch_bounds__(256) void nodeMM_kernel(
    const unsigned short* __restrict__ aggB, const unsigned short* __restrict__ xB,
    const unsigned short* __restrict__ pack, const float* __restrict__ bl,
    const int* __restrict__ batch, unsigned short* __restrict__ hout,
    float* __restrict__ gsum, unsigned* __restrict__ gmax) {
  int w = threadIdx.x >> 6;
  int lane = threadIdx.x & 63;
  int wbase = blockIdx.x * 64 + w * 16;
  bool active = (wbase < N_NODES);  // N_NODES % 16 == 0 -> whole wave valid

  f32x4 acc[8];
  if (active) {
    bf16x8 afrag[8];
    int row = wbase + (lane & 15);
    int koff = (lane >> 4) * 8;
    const unsigned short* ap = aggB + (size_t)row * EMB + koff;
    const unsigned short* xp = xB + (size_t)row * EMB + koff;
#pragma unroll
    for (int kb = 0; kb < 4; kb++) afrag[kb] = *reinterpret_cast<const bf16x8*>(ap + kb * 32);
#pragma unroll
    for (int kb = 0; kb < 4; kb++) afrag[4 + kb] = *reinterpret_cast<const bf16x8*>(xp + kb * 32);
#pragma unroll
    for (int cb = 0; cb < 8; cb++) {
      f32x4 a = {0.0f, 0.0f, 0.0f, 0.0f};
#pragma unroll
      for (int kb = 0; kb < 8; kb++) {
        bf16x8 b = *reinterpret_cast<const bf16x8*>(pack + ((size_t)(cb * 8 + kb) * 64 + lane) * 8);
        a = __builtin_amdgcn_mfma_f32_16x16x32_bf16(afrag[kb], b, a, 0, 0, 0);
      }
      acc[cb] = a;
    }
  }

  if constexpr (!POOL) {
    if (active) {
#pragma unroll
      for (int cb = 0; cb < 8; cb++) {
        int col = cb * 16 + (lane & 15);
        float bias = bl[col];
#pragma unroll
        for (int r = 0; r < 4; r++) {
          float v = acc[cb][r] + bias;
          if (RELU) v = fmaxf(v, 0.0f);
          int rowl = (lane >> 4) * 4 + r;  // C/D: col=lane&15, row=(lane>>4)*4+r
          hout[(size_t)(wbase + rowl) * EMB + col] = f2bf(v);
        }
      }
    }
  } else {
    __shared__ float sh[64][130];
    __shared__ int sBatch[64];
    if (threadIdx.x < 64) {
      int node = blockIdx.x * 64 + threadIdx.x;
      sBatch[threadIdx.x] = batch[node < N_NODES ? node : (N_NODES - 1)];
    }
    if (active) {
#pragma unroll
      for (int cb = 0; cb < 8; cb++) {
        int col = cb * 16 + (lane & 15);
        float bias = bl[col];
#pragma unroll
        for (int r = 0; r < 4; r++) {
          float v = acc[cb][r] + bias;
          if (RELU) v = fmaxf(v, 0.0f);
          sh[w * 16 + (lane >> 4) * 4 + r][col] = v;
        }
      }
    }
    __syncthreads();
    // Segment reduction: thread t owns column (t&127), rows half*32..+31.
    int col = threadIdx.x & 127;
    int half = threadIdx.x >> 7;
    int nbase = blockIdx.x * 64 + half * 32;
    float rs = 0.0f, rm = -INFINITY;
    int cur = -1;
    for (int r = 0; r < 32; r++) {
      if (nbase + r >= N_NODES) break;
      int b = sBatch[half * 32 + r];
      float v = sh[half * 32 + r][col];
      if (b != cur) {
        if (cur >= 0) {
          atomicAdd(&gsum[cur * EMB + col], rs);
          atomicMax(&gmax[cur * EMB + col], fkey(rm));
        }
        cur = b; rs = 0.0f; rm = -INFINITY;
      }
      rs += v;
      rm = fmaxf(rm, v);
    }
    if (cur >= 0) {
      atomicAdd(&gsum[cur * EMB + col], rs);
      atomicMax(&gmax[cur * EMB + col], fkey(rm));
    }
  }
}

// batch_idx is SORTED -> per-graph counts via binary search, no atomics.
__global__ __launch_bounds__(128) void gcnt_kernel(const int* __restrict__ batch,
                                                   float* __restrict__ gcnt) {
  __shared__ int lb[129];
  int g = threadIdx.x;
  int lo = 0, hi = N_NODES;
  while (lo < hi) {
    int mid = (lo + hi) >> 1;
    if (batch[mid] < g) lo = mid + 1; else hi = mid;
  }
  lb[g] = lo;
  if (g == 0) lb[128] = N_NODES;
  __syncthreads();
  gcnt[g] = (float)(lb[g + 1] - lb[g]);
}

// One block per graph, 128 threads = one per embedding dim.
__global__ __launch_bounds__(128) void readout_kernel(
    const float* __restrict__ gsum, const unsigned* __restrict__ gmax,
    const float* __restrict__ gcnt, const float* __restrict__ gfeat,
    const float* __restrict__ Wg, const float* __restrict__ bg,
    const float* __restrict__ Wo, const float* __restrict__ bo,
    float* __restrict__ out) {
  int g = blockIdx.x, d = threadIdx.x;
  float mean = gsum[g * EMB + d] / fmaxf(gcnt[g], 1.0f);
  float mx = fkey_inv(gmax[g * EMB + d]);
  float gfe = bg[d];
#pragma unroll
  for (int k = 0; k < G_FEAT; k++) gfe += gfeat[g * G_FEAT + k] * Wg[k * EMB + d];
  float l0 = mean * Wo[d * 2 + 0] + mx * Wo[(EMB + d) * 2 + 0] +
             gfe * Wo[(2 * EMB + d) * 2 + 0];
  float l1 = mean * Wo[d * 2 + 1] + mx * Wo[(EMB + d) * 2 + 1] +
             gfe * Wo[(2 * EMB + d) * 2 + 1];
  __shared__ float s0[128], s1[128];
  s0[d] = l0; s1[d] = l1;
  __syncthreads();
  for (int off = 64; off > 0; off >>= 1) {
    if (d < off) { s0[d] += s0[d + off]; s1[d] += s1[d + off]; }
    __syncthreads();
  }
  if (d == 0) {
    float a = s0[0] + bo[0];
    float b = s1[0] + bo[1];
    float m = fmaxf(a, b);
    float lse = m + logf(expf(a - m) + expf(b - m));
    out[g * 2 + 0] = a - lse;
    out[g * 2 + 1] = b - lse;
  }
}

extern "C" void kernel_launch(void* const* d_in, const int* in_sizes, int n_in,
                              void* d_out, int out_size, void* d_ws,
                              size_t ws_size, hipStream_t stream) {
  const float* x     = (const float*)d_in[0];
  const int*   edges = (const int*)d_in[1];
  const int*   batch = (const int*)d_in[2];
  const float* gfeat = (const float*)d_in[3];
  const float* W_l0  = (const float*)d_in[4];
  const float* b_l0  = (const float*)d_in[5];
  const float* W_r0  = (const float*)d_in[6];
  const float* W_l1  = (const float*)d_in[7];
  const float* b_l1  = (const float*)d_in[8];
  const float* W_r1  = (const float*)d_in[9];
  const float* W_g   = (const float*)d_in[10];
  const float* b_g   = (const float*)d_in[11];
  const float* W_o   = (const float*)d_in[12];
  const float* b_o   = (const float*)d_in[13];
  const int* srci = edges;
  const int* tgti = edges + N_EDGESC;

  // Workspace layout. Zeroed region first: [gsum | gmax | gcnt]
  char* ws = (char*)d_ws;
  float*    gsum     = (float*)ws;                          // 128*128
  unsigned* gmax     = (unsigned*)(gsum + N_GRAPHS * EMB);  // 128*128
  float*    gcnt     = (float*)(gmax + N_GRAPHS * EMB);     // 128
  unsigned short* xB   = (unsigned short*)(gcnt + N_GRAPHS);      // N*128 bf16
  unsigned short* aggB = xB + (size_t)N_NODES * EMB;              // N*128 bf16
  unsigned short* hB   = aggB + (size_t)N_NODES * EMB;            // N*128 bf16
  unsigned short* pack0 = hB + (size_t)N_NODES * EMB;             // 32768 bf16
  unsigned short* pack1 = pack0 + 8 * 8 * 64 * 8;                 // 32768 bf16
  int*      ebuf     = (int*)(pack1 + 8 * 8 * 64 * 8);      // E
  int*      rowstart = ebuf + N_EDGESC;                     // N+1
  int*      bucketBase = rowstart + N_NODES + 1;            // NBUK+1
  int*      tot      = bucketBase + NBUK + 4;               // NBUK (pad)
  // CSR-build scratch aliased into regions written only AFTER the build:
  int*      counts   = (int*)aggB;                          // NBLK_E*NBUK ints (<1.3MB)
  int*      offsets  = counts + NBLK_E * NBUK;              // NBLK_E*NBUK ints
  unsigned* bucketed = (unsigned*)hB;                       // E uints (6.4MB)

  // Zero gsum/gmax/gcnt only (131.5 KB).
  size_t zbytes = (size_t)((char*)xB - ws);
  hipMemsetAsync(d_ws, 0, zbytes, stream);

  dim3 b256(256);

  // Conversions / packing (small)
  f2bf_kernel<<<(N_NODES * EMB / 4 + 255) / 256, b256, 0, stream>>>(x, xB,
                                                                    N_NODES * EMB / 4);
  pack_kernel<<<16, b256, 0, stream>>>(W_l0, W_r0, pack0);
  pack_kernel<<<16, b256, 0, stream>>>(W_l1, W_r1, pack1);

  // Bucketed CSR build (shared by both layers)
  bhistA_kernel<<<NBLK_E, b256, 0, stream>>>(tgti, counts);
  bsumB1_kernel<<<NBUK, b256, 0, stream>>>(counts, tot);
  bbaseB_kernel<<<1, b256, 0, stream>>>(tot, bucketBase);
  boffB2_kernel<<<NBUK, b256, 0, stream>>>(counts, bucketBase, offsets);
  bscatC_kernel<<<NBLK_E, b256, 0, stream>>>(srci, tgti, offsets, bucketed);
  bcsrD_kernel<<<NBUK, b256, 0, stream>>>(bucketed, bucketBase, rowstart, ebuf);
  gcnt_kernel<<<1, 128, 0, stream>>>(batch, gcnt);

  int ngrid = (N_NODES + 63) / 64;   // 1563
  int agrid = (N_NODES + 7) / 8;     // 12500 (2 nodes/wave, 4 waves/block)

  // Layer 0
  aggb_kernel<<<agrid, b256, 0, stream>>>(xB, ebuf, rowstart, aggB);
  nodeMM_kernel<true, false><<<ngrid, b256, 0, stream>>>(
      aggB, xB, pack0, b_l0, nullptr, hB, nullptr, nullptr);

  // Layer 1
  aggb_kernel<<<agrid, b256, 0, stream>>>(hB, ebuf, rowstart, aggB);
  nodeMM_kernel<false, true><<<ngrid, b256, 0, stream>>>(
      aggB, hB, pack1, b_l1, batch, nullptr, gsum, gmax);

  // Readout
  readout_kernel<<<N_GRAPHS, 128, 0, stream>>>(gsum, gmax, gcnt, gfeat, W_g,
                                               b_g, W_o, b_o, (float*)d_out);
}

// Round 12
// 353.753 us; speedup vs baseline: 18.8469x; 1.0153x over previous
//
#include <hip/hip_runtime.h>

// Problem constants (match reference file)
#define N_NODES  100000
#define N_EDGESC 1600000
#define EMB      128
#define N_GRAPHS 128
#define G_FEAT   32

// Bucketed CSR build parameters
#define BUKSH    9                      // bucket = tgt >> 9 (512 nodes/bucket)
#define NBUK     196                    // ceil(100000 / 512)
#define CHUNK_E  2048
#define NBLK_E   ((N_EDGESC + CHUNK_E - 1) / CHUNK_E)  // 782

typedef __attribute__((ext_vector_type(8))) short bf16x8;
typedef __attribute__((ext_vector_type(4))) float f32x4;

// Order-preserving float -> uint key for atomicMax-based float max.
__device__ __forceinline__ unsigned fkey(float f) {
  unsigned u = __float_as_uint(f);
  return (u & 0x80000000u) ? ~u : (u | 0x80000000u);
}
__device__ __forceinline__ float fkey_inv(unsigned k) {
  return (k & 0x80000000u) ? __uint_as_float(k & 0x7FFFFFFFu)
                           : __uint_as_float(~k);
}
__device__ __forceinline__ float bf2f(unsigned short u) {
  return __uint_as_float(((unsigned)u) << 16);
}
__device__ __forceinline__ unsigned short f2bf(float f) {  // RNE
  unsigned u = __float_as_uint(f);
  u += 0x7fffu + ((u >> 16) & 1u);
  return (unsigned short)(u >> 16);
}

// ---------------- dtype conversion / weight packing ----------------

__global__ __launch_bounds__(256) void f2bf_kernel(const float* __restrict__ in,
                                                   unsigned short* __restrict__ out,
                                                   int n4) {
  int i = blockIdx.x * blockDim.x + threadIdx.x;
  if (i >= n4) return;
  float4 v = reinterpret_cast<const float4*>(in)[i];
  uint2 o;
  o.x = (unsigned)f2bf(v.x) | ((unsigned)f2bf(v.y) << 16);
  o.y = (unsigned)f2bf(v.z) | ((unsigned)f2bf(v.w) << 16);
  reinterpret_cast<uint2*>(out)[i] = o;
}

// Pack stacked weights [Wl(128x128); Wr(128x128)] -> MFMA B-fragment order:
// pack[((cb*8+kb)*64+lane)*8 + j] = W[k = kb*32+(lane>>4)*8+j][col = cb*16+(lane&15)]
__global__ __launch_bounds__(256) void pack_kernel(const float* __restrict__ Wl,
                                                   const float* __restrict__ Wr,
                                                   unsigned short* __restrict__ pack) {
  int id = blockIdx.x * blockDim.x + threadIdx.x;
  if (id >= 4096) return;
  int lane = id & 63;
  int kb = (id >> 6) & 7;
  int cb = id >> 9;
  int col = cb * 16 + (lane & 15);
  int k0 = kb * 32 + (lane >> 4) * 8;
  unsigned short v[8];
#pragma unroll
  for (int j = 0; j < 8; j++) {
    int k = k0 + j;
    float w = (k < 128) ? Wl[k * 128 + col] : Wr[(k - 128) * 128 + col];
    v[j] = f2bf(w);
  }
  uint4 o;
  o.x = (unsigned)v[0] | ((unsigned)v[1] << 16);
  o.y = (unsigned)v[2] | ((unsigned)v[3] << 16);
  o.z = (unsigned)v[4] | ((unsigned)v[5] << 16);
  o.w = (unsigned)v[6] | ((unsigned)v[7] << 16);
  *reinterpret_cast<uint4*>(pack + (size_t)id * 8) = o;
}

// ---------------- bucketed CSR build (write-locality-ordered) ----------------

// A: per-chunk LDS histogram over 196 coarse buckets.
__global__ __launch_bounds__(256) void bhistA_kernel(const int* __restrict__ tgti,
                                                     int* __restrict__ counts) {
  __shared__ int h[NBUK];
  for (int i = threadIdx.x; i < NBUK; i += 256) h[i] = 0;
  __syncthreads();
  int base = blockIdx.x * CHUNK_E;
  for (int i = threadIdx.x; i < CHUNK_E; i += 256) {
    int e = base + i;
    if (e < N_EDGESC) atomicAdd(&h[tgti[e] >> BUKSH], 1);
  }
  __syncthreads();
  for (int i = threadIdx.x; i < NBUK; i += 256)
    counts[blockIdx.x * NBUK + i] = h[i];
}

// B1: per-bucket totals. Block b tree-reduces its counts column.
__global__ __launch_bounds__(256) void bsumB1_kernel(const int* __restrict__ counts,
                                                     int* __restrict__ tot) {
  __shared__ int sh[256];
  int b = blockIdx.x;
  int t = threadIdx.x;
  int s = 0;
  for (int blk = t; blk < NBLK_E; blk += 256) s += counts[blk * NBUK + b];
  sh[t] = s;
  __syncthreads();
  for (int off = 128; off > 0; off >>= 1) {
    if (t < off) sh[t] += sh[t + off];
    __syncthreads();
  }
  if (t == 0) tot[b] = sh[0];
}

// B1b: exclusive scan of 196 totals -> bucketBase. One block (tiny).
__global__ __launch_bounds__(256) void bbaseB_kernel(const int* __restrict__ tot,
                                                     int* __restrict__ bucketBase) {
  __shared__ int sh[256];
  int t = threadIdx.x;
  int v = (t < NBUK) ? tot[t] : 0;
  sh[t] = v;
  __syncthreads();
  for (int off = 1; off < 256; off <<= 1) {
    int val = (t >= off) ? sh[t - off] : 0;
    __syncthreads();
    if (t >= off) sh[t] += val;
    __syncthreads();
  }
  if (t < NBUK) bucketBase[t] = sh[t] - v;
  if (t == 0) bucketBase[NBUK] = sh[NBUK - 1];  // == N_EDGESC
}

// B2: per-bucket exclusive scan over chunks -> stable offsets.
__global__ __launch_bounds__(256) void boffB2_kernel(const int* __restrict__ counts,
                                                     const int* __restrict__ bucketBase,
                                                     int* __restrict__ offsets) {
  __shared__ int sh[256];
  int b = blockIdx.x;
  int t = threadIdx.x;
  int v[4], s = 0;
#pragma unroll
  for (int i = 0; i < 4; i++) {
    int blk = t * 4 + i;
    v[i] = (blk < NBLK_E) ? counts[blk * NBUK + b] : 0;
    s += v[i];
  }
  sh[t] = s;
  __syncthreads();
  for (int off = 1; off < 256; off <<= 1) {
    int val = (t >= off) ? sh[t - off] : 0;
    __syncthreads();
    if (t >= off) sh[t] += val;
    __syncthreads();
  }
  int run = bucketBase[b] + sh[t] - s;
#pragma unroll
  for (int i = 0; i < 4; i++) {
    int blk = t * 4 + i;
    if (blk < NBLK_E) offsets[blk * NBUK + b] = run;
    run += v[i];
  }
}

// C: scatter packed (src | local_tgt<<17) into bucket-contiguous regions.
__global__ __launch_bounds__(256) void bscatC_kernel(const int* __restrict__ srci,
                                                     const int* __restrict__ tgti,
                                                     const int* __restrict__ offsets,
                                                     unsigned* __restrict__ bucketed) {
  __shared__ int cur[NBUK];
  for (int i = threadIdx.x; i < NBUK; i += 256)
    cur[i] = offsets[blockIdx.x * NBUK + i];
  __syncthreads();
  int base = blockIdx.x * CHUNK_E;
  for (int i = threadIdx.x; i < CHUNK_E; i += 256) {
    int e = base + i;
    if (e < N_EDGESC) {
      int t = tgti[e];
      int bk = t >> BUKSH;
      int pos = atomicAdd(&cur[bk], 1);
      bucketed[pos] = (unsigned)srci[e] |
                      ((unsigned)(t & ((1 << BUKSH) - 1)) << 17);
    }
  }
}

// D: one block per bucket -> per-node degree, rowstart, and ebuf fill
// (all writes land in this block's own 32 KB region: single-CU locality).
__global__ __launch_bounds__(256) void bcsrD_kernel(const unsigned* __restrict__ bucketed,
                                                    const int* __restrict__ bucketBase,
                                                    int* __restrict__ rowstart,
                                                    int* __restrict__ ebuf) {
  __shared__ int deg[512];
  __shared__ int pre[512];
  __shared__ int sh2[256];
  int bk = blockIdx.x;
  int node0 = bk << BUKSH;
  int nn = min(512, N_NODES - node0);
  int beg = bucketBase[bk], end = bucketBase[bk + 1];
  for (int i = threadIdx.x; i < 512; i += 256) deg[i] = 0;
  __syncthreads();
  for (int j = beg + threadIdx.x; j < end; j += 256)
    atomicAdd(&deg[bucketed[j] >> 17], 1);
  __syncthreads();
  // block exclusive scan over 512 (2 per thread)
  int t = threadIdx.x;
  int v0 = deg[2 * t], v1 = deg[2 * t + 1];
  sh2[t] = v0 + v1;
  __syncthreads();
  for (int off = 1; off < 256; off <<= 1) {
    int val = (t >= off) ? sh2[t - off] : 0;
    __syncthreads();
    if (t >= off) sh2[t] += val;
    __syncthreads();
  }
  int ex = sh2[t] - v0 - v1;
  pre[2 * t] = ex;
  pre[2 * t + 1] = ex + v0;
  __syncthreads();
  for (int i = threadIdx.x; i < nn; i += 256) rowstart[node0 + i] = beg + pre[i];
  if (bk == 0 && threadIdx.x == 0) rowstart[N_NODES] = N_EDGESC;
  // reuse deg[] as local cursor = pre[]
  for (int i = threadIdx.x; i < 512; i += 256) deg[i] = pre[i];
  __syncthreads();
  for (int j = beg + threadIdx.x; j < end; j += 256) {
    unsigned p = bucketed[j];
    int ln = p >> 17;
    int pos = atomicAdd(&deg[ln], 1);
    ebuf[beg + pos] = (int)(p & 0x1FFFFu);
  }
}

// ---------------- mean aggregation (bf16 gather, no atomics) ----------------
// 2 nodes per wave: half-wave of 32 lanes per node, lane owns 4 dims (8 B).
// Predicated x8 unroll: NO serial tail — every iteration issues 8 independent
// row gathers (index clamped, result masked to 0 past end; +0.0f is identity).
__global__ __launch_bounds__(256) void aggb_kernel(const unsigned short* __restrict__ featB,
                                                   const int* __restrict__ ebuf,
                                                   const int* __restrict__ rowstart,
                                                   unsigned short* __restrict__ aggB) {
  int wid = (blockIdx.x * 256 + threadIdx.x) >> 6;  // global wave id
  int lane = threadIdx.x & 63;
  int node = wid * 2 + (lane >> 5);
  if (node >= N_NODES) return;
  int l = lane & 31;
  int beg = rowstart[node], end = rowstart[node + 1];
  const unsigned short* fb = featB + l * 4;  // lane's 4-dim slice (8 B)
  float a0 = 0.0f, a1 = 0.0f, a2 = 0.0f, a3 = 0.0f;
  for (int j = beg; j < end; j += 8) {
    int idx[8];
    uint2 u[8];
#pragma unroll
    for (int i = 0; i < 8; i++) idx[i] = min(j + i, end - 1);
#pragma unroll
    for (int i = 0; i < 8; i++)
      u[i] = *reinterpret_cast<const uint2*>(fb + (size_t)ebuf[idx[i]] * EMB);
#pragma unroll
    for (int i = 0; i < 8; i++) {
      bool ok = (j + i) < end;
      unsigned ux = ok ? u[i].x : 0u;
      unsigned uy = ok ? u[i].y : 0u;
      a0 += bf2f((unsigned short)(ux & 0xffffu));
      a1 += bf2f((unsigned short)(ux >> 16));
      a2 += bf2f((unsigned short)(uy & 0xffffu));
      a3 += bf2f((unsigned short)(uy >> 16));
    }
  }
  float inv = 1.0f / fmaxf((float)(end - beg), 1.0f);
  uint2 o;
  o.x = (unsigned)f2bf(a0 * inv) | ((unsigned)f2bf(a1 * inv) << 16);
  o.y = (unsigned)f2bf(a2 * inv) | ((unsigned)f2bf(a3 * inv) << 16);
  *reinterpret_cast<uint2*>(aggB + (size_t)node * EMB + l * 4) = o;
}

// ---------------- node GEMM via MFMA: out = [relu]([agg|x] @ [Wl;Wr] + bl) ----
// 64 nodes/block, 4 waves x 16 rows. A-frags direct from global; B from pack.
// POOL: stage to LDS, segment-reduce per column (batch_idx sorted), few atomics.
template <bool RELU, bool POOL>
__global__ __launch_bounds__(256) void nodeMM_kernel(
    const unsigned short* __restrict__ aggB, const unsigned short* __restrict__ xB,
    const unsigned short* __restrict__ pack, const float* __restrict__ bl,
    const int* __restrict__ batch, unsigned short* __restrict__ hout,
    float* __restrict__ gsum, unsigned* __restrict__ gmax) {
  int w = threadIdx.x >> 6;
  int lane = threadIdx.x & 63;
  int wbase = blockIdx.x * 64 + w * 16;
  bool active = (wbase < N_NODES);  // N_NODES % 16 == 0 -> whole wave valid

  f32x4 acc[8];
  if (active) {
    bf16x8 afrag[8];
    int row = wbase + (lane & 15);
    int koff = (lane >> 4) * 8;
    const unsigned short* ap = aggB + (size_t)row * EMB + koff;
    const unsigned short* xp = xB + (size_t)row * EMB + koff;
#pragma unroll
    for (int kb = 0; kb < 4; kb++) afrag[kb] = *reinterpret_cast<const bf16x8*>(ap + kb * 32);
#pragma unroll
    for (int kb = 0; kb < 4; kb++) afrag[4 + kb] = *reinterpret_cast<const bf16x8*>(xp + kb * 32);
#pragma unroll
    for (int cb = 0; cb < 8; cb++) {
      f32x4 a = {0.0f, 0.0f, 0.0f, 0.0f};
#pragma unroll
      for (int kb = 0; kb < 8; kb++) {
        bf16x8 b = *reinterpret_cast<const bf16x8*>(pack + ((size_t)(cb * 8 + kb) * 64 + lane) * 8);
        a = __builtin_amdgcn_mfma_f32_16x16x32_bf16(afrag[kb], b, a, 0, 0, 0);
      }
      acc[cb] = a;
    }
  }

  if constexpr (!POOL) {
    if (active) {
#pragma unroll
      for (int cb = 0; cb < 8; cb++) {
        int col = cb * 16 + (lane & 15);
        float bias = bl[col];
#pragma unroll
        for (int r = 0; r < 4; r++) {
          float v = acc[cb][r] + bias;
          if (RELU) v = fmaxf(v, 0.0f);
          int rowl = (lane >> 4) * 4 + r;  // C/D: col=lane&15, row=(lane>>4)*4+r
          hout[(size_t)(wbase + rowl) * EMB + col] = f2bf(v);
        }
      }
    }
  } else {
    __shared__ float sh[64][130];
    __shared__ int sBatch[64];
    if (threadIdx.x < 64) {
      int node = blockIdx.x * 64 + threadIdx.x;
      sBatch[threadIdx.x] = batch[node < N_NODES ? node : (N_NODES - 1)];
    }
    if (active) {
#pragma unroll
      for (int cb = 0; cb < 8; cb++) {
        int col = cb * 16 + (lane & 15);
        float bias = bl[col];
#pragma unroll
        for (int r = 0; r < 4; r++) {
          float v = acc[cb][r] + bias;
          if (RELU) v = fmaxf(v, 0.0f);
          sh[w * 16 + (lane >> 4) * 4 + r][col] = v;
        }
      }
    }
    __syncthreads();
    // Segment reduction: thread t owns column (t&127), rows half*32..+31.
    int col = threadIdx.x & 127;
    int half = threadIdx.x >> 7;
    int nbase = blockIdx.x * 64 + half * 32;
    float rs = 0.0f, rm = -INFINITY;
    int cur = -1;
    for (int r = 0; r < 32; r++) {
      if (nbase + r >= N_NODES) break;
      int b = sBatch[half * 32 + r];
      float v = sh[half * 32 + r][col];
      if (b != cur) {
        if (cur >= 0) {
          atomicAdd(&gsum[cur * EMB + col], rs);
          atomicMax(&gmax[cur * EMB + col], fkey(rm));
        }
        cur = b; rs = 0.0f; rm = -INFINITY;
      }
      rs += v;
      rm = fmaxf(rm, v);
    }
    if (cur >= 0) {
      atomicAdd(&gsum[cur * EMB + col], rs);
      atomicMax(&gmax[cur * EMB + col], fkey(rm));
    }
  }
}

// batch_idx is SORTED -> per-graph counts via binary search, no atomics.
__global__ __launch_bounds__(128) void gcnt_kernel(const int* __restrict__ batch,
                                                   float* __restrict__ gcnt) {
  __shared__ int lb[129];
  int g = threadIdx.x;
  int lo = 0, hi = N_NODES;
  while (lo < hi) {
    int mid = (lo + hi) >> 1;
    if (batch[mid] < g) lo = mid + 1; else hi = mid;
  }
  lb[g] = lo;
  if (g == 0) lb[128] = N_NODES;
  __syncthreads();
  gcnt[g] = (float)(lb[g + 1] - lb[g]);
}

// One block per graph, 128 threads = one per embedding dim.
__global__ __launch_bounds__(128) void readout_kernel(
    const float* __restrict__ gsum, const unsigned* __restrict__ gmax,
    const float* __restrict__ gcnt, const float* __restrict__ gfeat,
    const float* __restrict__ Wg, const float* __restrict__ bg,
    const float* __restrict__ Wo, const float* __restrict__ bo,
    float* __restrict__ out) {
  int g = blockIdx.x, d = threadIdx.x;
  float mean = gsum[g * EMB + d] / fmaxf(gcnt[g], 1.0f);
  float mx = fkey_inv(gmax[g * EMB + d]);
  float gfe = bg[d];
#pragma unroll
  for (int k = 0; k < G_FEAT; k++) gfe += gfeat[g * G_FEAT + k] * Wg[k * EMB + d];
  float l0 = mean * Wo[d * 2 + 0] + mx * Wo[(EMB + d) * 2 + 0] +
             gfe * Wo[(2 * EMB + d) * 2 + 0];
  float l1 = mean * Wo[d * 2 + 1] + mx * Wo[(EMB + d) * 2 + 1] +
             gfe * Wo[(2 * EMB + d) * 2 + 1];
  __shared__ float s0[128], s1[128];
  s0[d] = l0; s1[d] = l1;
  __syncthreads();
  for (int off = 64; off > 0; off >>= 1) {
    if (d < off) { s0[d] += s0[d + off]; s1[d] += s1[d + off]; }
    __syncthreads();
  }
  if (d == 0) {
    float a = s0[0] + bo[0];
    float b = s1[0] + bo[1];
    float m = fmaxf(a, b);
    float lse = m + logf(expf(a - m) + expf(b - m));
    out[g * 2 + 0] = a - lse;
    out[g * 2 + 1] = b - lse;
  }
}

extern "C" void kernel_launch(void* const* d_in, const int* in_sizes, int n_in,
                              void* d_out, int out_size, void* d_ws,
                              size_t ws_size, hipStream_t stream) {
  const float* x     = (const float*)d_in[0];
  const int*   edges = (const int*)d_in[1];
  const int*   batch = (const int*)d_in[2];
  const float* gfeat = (const float*)d_in[3];
  const float* W_l0  = (const float*)d_in[4];
  const float* b_l0  = (const float*)d_in[5];
  const float* W_r0  = (const float*)d_in[6];
  const float* W_l1  = (const float*)d_in[7];
  const float* b_l1  = (const float*)d_in[8];
  const float* W_r1  = (const float*)d_in[9];
  const float* W_g   = (const float*)d_in[10];
  const float* b_g   = (const float*)d_in[11];
  const float* W_o   = (const float*)d_in[12];
  const float* b_o   = (const float*)d_in[13];
  const int* srci = edges;
  const int* tgti = edges + N_EDGESC;

  // Workspace layout. Zeroed region first: [gsum | gmax | gcnt]
  char* ws = (char*)d_ws;
  float*    gsum     = (float*)ws;                          // 128*128
  unsigned* gmax     = (unsigned*)(gsum + N_GRAPHS * EMB);  // 128*128
  float*    gcnt     = (float*)(gmax + N_GRAPHS * EMB);     // 128
  unsigned short* xB   = (unsigned short*)(gcnt + N_GRAPHS);      // N*128 bf16
  unsigned short* aggB = xB + (size_t)N_NODES * EMB;              // N*128 bf16
  unsigned short* hB   = aggB + (size_t)N_NODES * EMB;            // N*128 bf16
  unsigned short* pack0 = hB + (size_t)N_NODES * EMB;             // 32768 bf16
  unsigned short* pack1 = pack0 + 8 * 8 * 64 * 8;                 // 32768 bf16
  int*      ebuf     = (int*)(pack1 + 8 * 8 * 64 * 8);      // E
  int*      rowstart = ebuf + N_EDGESC;                     // N+1
  int*      bucketBase = rowstart + N_NODES + 1;            // NBUK+1
  int*      tot      = bucketBase + NBUK + 4;               // NBUK (pad)
  // CSR-build scratch aliased into regions written only AFTER the build:
  int*      counts   = (int*)aggB;                          // NBLK_E*NBUK ints (<1.3MB)
  int*      offsets  = counts + NBLK_E * NBUK;              // NBLK_E*NBUK ints
  unsigned* bucketed = (unsigned*)hB;                       // E uints (6.4MB)

  // Zero gsum/gmax/gcnt only (131.5 KB).
  size_t zbytes = (size_t)((char*)xB - ws);
  hipMemsetAsync(d_ws, 0, zbytes, stream);

  dim3 b256(256);

  // Conversions / packing (small)
  f2bf_kernel<<<(N_NODES * EMB / 4 + 255) / 256, b256, 0, stream>>>(x, xB,
                                                                    N_NODES * EMB / 4);
  pack_kernel<<<16, b256, 0, stream>>>(W_l0, W_r0, pack0);
  pack_kernel<<<16, b256, 0, stream>>>(W_l1, W_r1, pack1);

  // Bucketed CSR build (shared by both layers)
  bhistA_kernel<<<NBLK_E, b256, 0, stream>>>(tgti, counts);
  bsumB1_kernel<<<NBUK, b256, 0, stream>>>(counts, tot);
  bbaseB_kernel<<<1, b256, 0, stream>>>(tot, bucketBase);
  boffB2_kernel<<<NBUK, b256, 0, stream>>>(counts, bucketBase, offsets);
  bscatC_kernel<<<NBLK_E, b256, 0, stream>>>(srci, tgti, offsets, bucketed);
  bcsrD_kernel<<<NBUK, b256, 0, stream>>>(bucketed, bucketBase, rowstart, ebuf);
  gcnt_kernel<<<1, 128, 0, stream>>>(batch, gcnt);

  int ngrid = (N_NODES + 63) / 64;   // 1563
  int agrid = (N_NODES + 7) / 8;     // 12500 (2 nodes/wave, 4 waves/block)

  // Layer 0
  aggb_kernel<<<agrid, b256, 0, stream>>>(xB, ebuf, rowstart, aggB);
  nodeMM_kernel<true, false><<<ngrid, b256, 0, stream>>>(
      aggB, xB, pack0, b_l0, nullptr, hB, nullptr, nullptr);

  // Layer 1
  aggb_kernel<<<agrid, b256, 0, stream>>>(hB, ebuf, rowstart, aggB);
  nodeMM_kernel<false, true><<<ngrid, b256, 0, stream>>>(
      aggB, hB, pack1, b_l1, batch, nullptr, gsum, gmax);

  // Readout
  readout_kernel<<<N_GRAPHS, 128, 0, stream>>>(gsum, gmax, gcnt, gfeat, W_g,
                                               b_g, W_o, b_o, (float*)d_out);
}